// Round 11
// baseline (7803.412 us; speedup 1.0000x reference)
//
#include <hip/hip_runtime.h>
#include <math.h>

#define HD   256
#define RB   8      // batch rows per block -> grid 256 = 1 block/CU
#define TB   1024   // 16 waves, 4/SIMD; wave covers 4 W-rows x 4 output-groups
#define TT   64
#define NST  32
#define BSZ  2048

// ---------------- math helpers ----------------
__device__ __forceinline__ float sigmoidf_(float x) {
    return 1.0f / (1.0f + __expf(-x));
}
__device__ __forceinline__ float tanhf_(float x) {
    float e = __expf(2.0f * x);
    return 1.0f - 2.0f / (e + 1.0f);
}
__device__ __forceinline__ float seluf_(float x) {
    const float a = 1.6732632423543772f, s = 1.0507009873554805f;
    return x > 0.0f ? s * x : s * a * (__expf(x) - 1.0f);
}
__device__ __forceinline__ float erfinvf_(float x) {
    float w = -log1pf(-x * x);
    float p;
    if (w < 5.0f) {
        w -= 2.5f;
        p = 2.81022636e-08f;
        p = fmaf(p, w, 3.43273939e-07f);
        p = fmaf(p, w, -3.5233877e-06f);
        p = fmaf(p, w, -4.39150654e-06f);
        p = fmaf(p, w, 0.00021858087f);
        p = fmaf(p, w, -0.00125372503f);
        p = fmaf(p, w, -0.00417768164f);
        p = fmaf(p, w, 0.246640727f);
        p = fmaf(p, w, 1.50140941f);
    } else {
        w = sqrtf(w) - 3.0f;
        p = -0.000200214257f;
        p = fmaf(p, w, 0.000100950558f);
        p = fmaf(p, w, 0.00134934322f);
        p = fmaf(p, w, -0.00367342844f);
        p = fmaf(p, w, 0.00573950773f);
        p = fmaf(p, w, -0.0076224613f);
        p = fmaf(p, w, 0.00943887047f);
        p = fmaf(p, w, 1.00167406f);
        p = fmaf(p, w, 2.83297682f);
    }
    return p * x;
}

#define TF_ROUND(x0, x1, R) { x0 += x1; x1 = (x1 << (R)) | (x1 >> (32 - (R))); x1 ^= x0; }

__device__ __forceinline__ void threefry_(unsigned c0, unsigned c1, unsigned& r0, unsigned& r1) {
    const unsigned ks0 = 0u, ks1 = 42u, ks2 = 0x1BD11BDAu ^ 0u ^ 42u;
    unsigned x0 = c0 + ks0, x1 = c1 + ks1;
    TF_ROUND(x0,x1,13) TF_ROUND(x0,x1,15) TF_ROUND(x0,x1,26) TF_ROUND(x0,x1,6)
    x0 += ks1; x1 += ks2 + 1u;
    TF_ROUND(x0,x1,17) TF_ROUND(x0,x1,29) TF_ROUND(x0,x1,16) TF_ROUND(x0,x1,24)
    x0 += ks2; x1 += ks0 + 2u;
    TF_ROUND(x0,x1,13) TF_ROUND(x0,x1,15) TF_ROUND(x0,x1,26) TF_ROUND(x0,x1,6)
    x0 += ks0; x1 += ks1 + 3u;
    TF_ROUND(x0,x1,17) TF_ROUND(x0,x1,29) TF_ROUND(x0,x1,16) TF_ROUND(x0,x1,24)
    x0 += ks1; x1 += ks2 + 4u;
    TF_ROUND(x0,x1,13) TF_ROUND(x0,x1,15) TF_ROUND(x0,x1,26) TF_ROUND(x0,x1,6)
    x0 += ks2; x1 += ks0 + 5u;
    r0 = x0; r1 = x1;
}

// eps[i]: bits = o0 ^ o1 of threefry2x32(key(0,42), (0, i))  [verified round 5]
__device__ __forceinline__ float jax_normal_(unsigned i) {
    unsigned o0, o1;
    threefry_(0u, i, o0, o1);
    unsigned bits = o0 ^ o1;
    unsigned fb = (bits >> 9) | 0x3F800000u;
    float f = __uint_as_float(fb) - 1.0f;
    const float lo = -0.99999994f;
    float u = f * 2.0f + lo;
    u = fmaxf(lo, u);
    return 1.41421356237f * erfinvf_(u);
}

typedef const float (*cmat)[HD];

// ---------------- wave-internal full-k 256x256 matmul ----------------
// W [256+ out][256 k] as float4 [out][64]. Wave w covers rows jjb = w*4+jh (jh=l>>4);
// lane kc = l&15 reads 16 CONSECUTIVE float4s per row (256B contiguous per 16 lanes).
// Output groups m=0..3: rows jjb + 64*m. Each W element read exactly once per block.
// 4-step shfl_xor butterfly (1,2,4,8) reduces full k=256 intra-wave; lane keeps
// output jj = jjb + 64*(kc&3), rows {rp*2, rp*2+1} where rp = kc>>2. No LDS exchange.
__device__ __forceinline__ void qmm(const float4* __restrict__ W4, cmat in,
                                    float& r0, float& r1,
                                    const int jjb, const int kc, const int rp, const int m)
{
    float a0[RB], a1[RB], a2[RB], a3[RB];
#pragma unroll
    for (int r = 0; r < RB; ++r) { a0[r] = 0.f; a1[r] = 0.f; a2[r] = 0.f; a3[r] = 0.f; }
    const float4* wp = W4 + (size_t)jjb * 64 + kc;
#pragma unroll 2
    for (int g = 0; g < 4; ++g) {
        const float4 w0 = wp[g * 16];
        const float4 w1 = wp[g * 16 + 4096];    // +64 rows
        const float4 w2 = wp[g * 16 + 8192];    // +128 rows
        const float4 w3 = wp[g * 16 + 12288];   // +192 rows
        const int ki = (kc + g * 16) * 4;
#pragma unroll
        for (int r = 0; r < RB; ++r) {
            const float4 av = *(const float4*)(&in[r][ki]);
            a0[r] = fmaf(av.w, w0.w, fmaf(av.z, w0.z, fmaf(av.y, w0.y, fmaf(av.x, w0.x, a0[r]))));
            a1[r] = fmaf(av.w, w1.w, fmaf(av.z, w1.z, fmaf(av.y, w1.y, fmaf(av.x, w1.x, a1[r]))));
            a2[r] = fmaf(av.w, w2.w, fmaf(av.z, w2.z, fmaf(av.y, w2.y, fmaf(av.x, w2.x, a2[r]))));
            a3[r] = fmaf(av.w, w3.w, fmaf(av.z, w3.z, fmaf(av.y, w3.y, fmaf(av.x, w3.x, a3[r]))));
        }
    }
    float mine[RB];
#pragma unroll
    for (int r = 0; r < RB; ++r) {
        float v0 = a0[r];
        v0 += __shfl_xor(v0, 1); v0 += __shfl_xor(v0, 2);
        v0 += __shfl_xor(v0, 4); v0 += __shfl_xor(v0, 8);
        float v1 = a1[r];
        v1 += __shfl_xor(v1, 1); v1 += __shfl_xor(v1, 2);
        v1 += __shfl_xor(v1, 4); v1 += __shfl_xor(v1, 8);
        float v2 = a2[r];
        v2 += __shfl_xor(v2, 1); v2 += __shfl_xor(v2, 2);
        v2 += __shfl_xor(v2, 4); v2 += __shfl_xor(v2, 8);
        float v3 = a3[r];
        v3 += __shfl_xor(v3, 1); v3 += __shfl_xor(v3, 2);
        v3 += __shfl_xor(v3, 4); v3 += __shfl_xor(v3, 8);
        mine[r] = (m == 0) ? v0 : (m == 1) ? v1 : (m == 2) ? v2 : v3;
    }
    r0 = (rp == 0) ? mine[0] : (rp == 1) ? mine[2] : (rp == 2) ? mine[4] : mine[6];
    r1 = (rp == 0) ? mine[1] : (rp == 1) ? mine[3] : (rp == 2) ? mine[5] : mine[7];
}

// ---------------- fused pipeline kernel ----------------
__global__ __launch_bounds__(TB) void fused_kernel(
    const float* __restrict__ x,      // [2048][64][4]
    const float* __restrict__ meta,   // [2048][4]
    const float* __restrict__ W_ih,   // [768][8]
    const float* __restrict__ W_hh,   // [768][256]
    const float* __restrict__ b_ih,   // [768]
    const float* __restrict__ b_hh,   // [768]
    const float* __restrict__ eW1,    // [256][256]
    const float* __restrict__ eb1,    // [256]
    const float* __restrict__ eW2,    // [512][256]
    const float* __restrict__ eb2,    // [512]
    const float* __restrict__ oW1, const float* __restrict__ ob1,
    const float* __restrict__ oW2, const float* __restrict__ ob2,
    const float* __restrict__ oW3, const float* __restrict__ ob3,
    const float* __restrict__ oW4, const float* __restrict__ ob4,
    const float* __restrict__ outW,   // [260]
    const float* __restrict__ outb,   // [1]
    float* __restrict__ out)          // [2048]
{
    const int tid = threadIdx.x;
    const int l   = tid & 63;
    const int w   = tid >> 6;            // wave 0..15
    const int jh  = l >> 4;              // 0..3
    const int kc  = l & 15;              // k-lane
    const int jjb = w * 4 + jh;          // 0..63
    const int m   = kc & 3;
    const int rp  = kc >> 2;             // row-pair owner
    const int jj  = jjb + 64 * m;        // owned output
    const int R0  = rp * 2, R1 = rp * 2 + 1;   // owned rows
    const int b0  = blockIdx.x * RB;

    __shared__ float h0[RB][HD];
    __shared__ float h1[RB][HD];
    __shared__ float tA[RB][HD];
    __shared__ float tB[RB][HD];
    __shared__ float ytmp[RB][HD];
    __shared__ float xall[RB][TT * 4];
    __shared__ float meta_s[RB][4];
    __shared__ float dt_s[RB];
    __shared__ float red[TB];
    // ~54 KB LDS

    const float4* Whh4 = (const float4*)W_hh;
    const float4* E1f4 = (const float4*)eW1;
    const float4* E2f4 = (const float4*)eW2;
    const float4* O1f4 = (const float4*)oW1;
    const float4* O2f4 = (const float4*)oW2;
    const float4* O3f4 = (const float4*)oW3;
    const float4* O4f4 = (const float4*)oW4;

    cmat tAc = (cmat)tA, tBc = (cmat)tB, ytc = (cmat)ytmp;

    // ---- stage x, meta; zero h0 ----
#pragma unroll
    for (int i = 0; i < 2; ++i) {
        int idx = tid + i * TB;          // 0..2047
        int r = idx >> 8, c = idx & 255;
        xall[r][c] = x[(size_t)(b0 + r) * 256 + c];
    }
    if (tid < RB * 4) { int r = tid >> 2, mm = tid & 3; meta_s[r][mm] = meta[(b0 + r) * 4 + mm]; }
    if (tid < 2 * HD) { int r = tid >> 8, c = tid & 255; h0[r][c] = 0.0f; h0[r + 2][c] = 0.0f;
                        h0[r + 4][c] = 0.0f; h0[r + 6][c] = 0.0f; }
    __syncthreads();
    if (tid < RB) dt_s[tid] = (xall[tid][TT * 4 - 4] - xall[tid][0]) * (1.0f / (float)NST);

    // ---- GRU per-lane x-side constants for owned output jj ----
    float wir[4], wiz[4], win[4];
#pragma unroll
    for (int d = 0; d < 4; ++d) {
        wir[d] = W_ih[(size_t)jj * 8 + d];
        wiz[d] = W_ih[(size_t)(jj + 256) * 8 + d];
        win[d] = W_ih[(size_t)(jj + 512) * 8 + d];
    }
    float base_r[2], base_z[2], base_xn[2];
    {
        float mwr[4], mwz[4], mwn[4];
#pragma unroll
        for (int mm = 0; mm < 4; ++mm) {
            mwr[mm] = W_ih[(size_t)jj * 8 + 4 + mm];
            mwz[mm] = W_ih[(size_t)(jj + 256) * 8 + 4 + mm];
            mwn[mm] = W_ih[(size_t)(jj + 512) * 8 + 4 + mm];
        }
        const float bir = b_ih[jj], biz = b_ih[jj + 256], bin_ = b_ih[jj + 512];
        const float bhr = b_hh[jj], bhz = b_hh[jj + 256];
#pragma unroll
        for (int r = 0; r < 2; ++r) {
            const int R = R0 + r;
            float sr = bir + bhr, sz = biz + bhz, sn = bin_;
#pragma unroll
            for (int mm = 0; mm < 4; ++mm) {
                float mv = meta_s[R][mm];
                sr = fmaf(mv, mwr[mm], sr);
                sz = fmaf(mv, mwz[mm], sz);
                sn = fmaf(mv, mwn[mm], sn);
            }
            base_r[r] = sr; base_z[r] = sz; base_xn[r] = sn;
        }
    }
    const float bhn = b_hh[512 + jj];

    // ---- GRU: 64 steps, ping-pong h0/h1, ONE barrier per step ----
    float (*hc)[HD] = h0;
    float (*hn)[HD] = h1;
#pragma unroll 1
    for (int t = 0; t < TT; ++t) {
        float aR0, aR1, aZ0, aZ1, aN0, aN1;
        qmm(Whh4,         (cmat)hc, aR0, aR1, jjb, kc, rp, m);
        qmm(Whh4 + 16384, (cmat)hc, aZ0, aZ1, jjb, kc, rp, m);
        qmm(Whh4 + 32768, (cmat)hc, aN0, aN1, jjb, kc, rp, m);
#pragma unroll
        for (int r = 0; r < 2; ++r) {
            const int R = R0 + r;
            float xr = base_r[r], xz = base_z[r], xn = base_xn[r];
#pragma unroll
            for (int d = 0; d < 4; ++d) {
                float xv = xall[R][t * 4 + d];
                xr = fmaf(xv, wir[d], xr);
                xz = fmaf(xv, wiz[d], xz);
                xn = fmaf(xv, win[d], xn);
            }
            float aRv = r ? aR1 : aR0, aZv = r ? aZ1 : aZ0, aNv = r ? aN1 : aN0;
            float rg = sigmoidf_(xr + aRv);
            float zg = sigmoidf_(xz + aZv);
            float ng = tanhf_(fmaf(rg, bhn + aNv, xn));
            float hp = hc[R][jj];
            hn[R][jj] = fmaf(zg, hp - ng, ng);
        }
        __syncthreads();
        float (*tmp)[HD] = hc; hc = hn; hn = tmp;
    }
    // final h in h0 (even number of swaps)

    // ---- encoder + sample y0 into h0 ----
    {
        float a0, a1;
        qmm(E1f4, (cmat)h0, a0, a1, jjb, kc, rp, m);
        const float eb1j = eb1[jj];
        tA[R0][jj] = fmaxf(a0 + eb1j, 0.0f);
        tA[R1][jj] = fmaxf(a1 + eb1j, 0.0f);
        __syncthreads();

        float aM0, aM1, aS0, aS1;
        qmm(E2f4,            tAc, aM0, aM1, jjb, kc, rp, m);
        qmm(E2f4 + 256 * 64, tAc, aS0, aS1, jjb, kc, rp, m);
        const float bm = eb2[jj], bs = eb2[256 + jj];
        {
            float e0 = jax_normal_((unsigned)((b0 + R0) * HD + jj));
            float e1 = jax_normal_((unsigned)((b0 + R1) * HD + jj));
            h0[R0][jj] = fmaf(e0, aS0 + bs, aM0 + bm);
            h0[R1][jj] = fmaf(e1, aS1 + bs, aM1 + bm);
        }
        __syncthreads();
    }

    // ---- dopri5 ----
    const float A21 = (float)(1.0/5.0);
    const float A31 = (float)(3.0/40.0),      A32 = (float)(9.0/40.0);
    const float A41 = (float)(44.0/45.0),     A42 = (float)(-56.0/15.0),    A43 = (float)(32.0/9.0);
    const float A51 = (float)(19372.0/6561.0),A52 = (float)(-25360.0/2187.0),
                A53 = (float)(64448.0/6561.0),A54 = (float)(-212.0/729.0);
    const float A61 = (float)(9017.0/3168.0), A62 = (float)(-355.0/33.0),
                A63 = (float)(46732.0/5247.0),A64 = (float)(49.0/176.0),    A65 = (float)(-5103.0/18656.0);
    const float B1f = (float)(35.0/384.0),    B3f = (float)(500.0/1113.0),  B4f = (float)(125.0/192.0),
                B5f = (float)(-2187.0/6784.0),B6f = (float)(11.0/84.0);

    const float ob1j = ob1[jj], ob2j = ob2[jj], ob3j = ob3[jj], ob4j = ob4[jj];
    const float dt0 = dt_s[R0], dt1 = dt_s[R1];
    float k1[2], k2[2], k3[2], k4[2], k5[2], k6[2];

#pragma unroll 1
    for (int st = 0; st < NST; ++st) {
#pragma unroll 1
        for (int stage = 0; stage < 6; ++stage) {
            cmat yin = (stage == 0) ? (cmat)h0 : ytc;
            float a0, a1;
            qmm(O1f4, yin, a0, a1, jjb, kc, rp, m);
            tA[R0][jj] = seluf_(a0 + ob1j);
            tA[R1][jj] = seluf_(a1 + ob1j);
            __syncthreads();
            qmm(O2f4, tAc, a0, a1, jjb, kc, rp, m);
            tB[R0][jj] = seluf_(a0 + ob2j);
            tB[R1][jj] = seluf_(a1 + ob2j);
            __syncthreads();
            qmm(O3f4, tBc, a0, a1, jjb, kc, rp, m);
            tA[R0][jj] = seluf_(a0 + ob3j);
            tA[R1][jj] = seluf_(a1 + ob3j);
            __syncthreads();
            qmm(O4f4, tAc, a0, a1, jjb, kc, rp, m);

            switch (stage) {
            case 0:
                k1[0] = a0 + ob4j; k1[1] = a1 + ob4j;
                ytmp[R0][jj] = fmaf(dt0, A21 * k1[0], h0[R0][jj]);
                ytmp[R1][jj] = fmaf(dt1, A21 * k1[1], h0[R1][jj]);
                break;
            case 1:
                k2[0] = a0 + ob4j; k2[1] = a1 + ob4j;
                ytmp[R0][jj] = fmaf(dt0, fmaf(A32, k2[0], A31 * k1[0]), h0[R0][jj]);
                ytmp[R1][jj] = fmaf(dt1, fmaf(A32, k2[1], A31 * k1[1]), h0[R1][jj]);
                break;
            case 2:
                k3[0] = a0 + ob4j; k3[1] = a1 + ob4j;
                ytmp[R0][jj] = fmaf(dt0, fmaf(A43, k3[0], fmaf(A42, k2[0], A41 * k1[0])), h0[R0][jj]);
                ytmp[R1][jj] = fmaf(dt1, fmaf(A43, k3[1], fmaf(A42, k2[1], A41 * k1[1])), h0[R1][jj]);
                break;
            case 3:
                k4[0] = a0 + ob4j; k4[1] = a1 + ob4j;
                ytmp[R0][jj] = fmaf(dt0, fmaf(A54, k4[0], fmaf(A53, k3[0], fmaf(A52, k2[0], A51 * k1[0]))), h0[R0][jj]);
                ytmp[R1][jj] = fmaf(dt1, fmaf(A54, k4[1], fmaf(A53, k3[1], fmaf(A52, k2[1], A51 * k1[1]))), h0[R1][jj]);
                break;
            case 4:
                k5[0] = a0 + ob4j; k5[1] = a1 + ob4j;
                ytmp[R0][jj] = fmaf(dt0, fmaf(A65, k5[0], fmaf(A64, k4[0],
                               fmaf(A63, k3[0], fmaf(A62, k2[0], A61 * k1[0])))), h0[R0][jj]);
                ytmp[R1][jj] = fmaf(dt1, fmaf(A65, k5[1], fmaf(A64, k4[1],
                               fmaf(A63, k3[1], fmaf(A62, k2[1], A61 * k1[1])))), h0[R1][jj]);
                break;
            default:
                k6[0] = a0 + ob4j; k6[1] = a1 + ob4j;
                h0[R0][jj] = fmaf(dt0, fmaf(B6f, k6[0], fmaf(B5f, k5[0],
                             fmaf(B4f, k4[0], fmaf(B3f, k3[0], B1f * k1[0])))), h0[R0][jj]);
                h0[R1][jj] = fmaf(dt1, fmaf(B6f, k6[1], fmaf(B5f, k5[1],
                             fmaf(B4f, k4[1], fmaf(B3f, k3[1], B1f * k1[1])))), h0[R1][jj]);
                break;
            }
            __syncthreads();
        }
    }

    // ---- output head: 4 rows per pass ----
#pragma unroll 1
    for (int rp4 = 0; rp4 < 2; ++rp4) {
        const int R = rp4 * 4 + (tid >> 8);
        const int t8 = tid & 255;
        red[tid] = h0[R][t8] * outW[t8];
        __syncthreads();
        for (int sw = 128; sw > 0; sw >>= 1) {
            if (t8 < sw) red[tid] += red[tid + sw];
            __syncthreads();
        }
        if (t8 == 0) {
            float acc = red[tid] + outb[0];
#pragma unroll
            for (int mm = 0; mm < 4; ++mm) acc = fmaf(meta_s[R][mm], outW[HD + mm], acc);
            out[b0 + R] = acc;
        }
        __syncthreads();
    }
}

extern "C" void kernel_launch(void* const* d_in, const int* in_sizes, int n_in,
                              void* d_out, int out_size, void* d_ws, size_t ws_size,
                              hipStream_t stream) {
    const float* x    = (const float*)d_in[0];
    const float* meta = (const float*)d_in[1];
    const float* W_ih = (const float*)d_in[2];
    const float* W_hh = (const float*)d_in[3];
    const float* b_ih = (const float*)d_in[4];
    const float* b_hh = (const float*)d_in[5];
    const float* eW1  = (const float*)d_in[6];
    const float* eb1  = (const float*)d_in[7];
    const float* eW2  = (const float*)d_in[8];
    const float* eb2  = (const float*)d_in[9];
    const float* oW1  = (const float*)d_in[10];
    const float* ob1  = (const float*)d_in[11];
    const float* oW2  = (const float*)d_in[12];
    const float* ob2  = (const float*)d_in[13];
    const float* oW3  = (const float*)d_in[14];
    const float* ob3  = (const float*)d_in[15];
    const float* oW4  = (const float*)d_in[16];
    const float* ob4  = (const float*)d_in[17];
    const float* outW = (const float*)d_in[18];
    const float* outb = (const float*)d_in[19];

    fused_kernel<<<BSZ / RB, TB, 0, stream>>>(x, meta, W_ih, W_hh, b_ih, b_hh,
                                              eW1, eb1, eW2, eb2,
                                              oW1, ob1, oW2, ob2, oW3, ob3, oW4, ob4,
                                              outW, outb, (float*)d_out);
}

// Round 12
// 5902.926 us; speedup vs baseline: 1.3220x; 1.3220x over previous
//
#include <hip/hip_runtime.h>
#include <math.h>

#define HD   256
#define RB   8      // batch rows per block -> grid 256 = 1 block/CU
#define TB   1024   // 16 waves, 4/SIMD; kh = tid>>8 = k-quarter, owns rows kh*2..kh*2+1
#define TT   64
#define NST  32
#define BSZ  2048

// ---------------- math helpers ----------------
__device__ __forceinline__ float sigmoidf_(float x) {
    return 1.0f / (1.0f + __expf(-x));
}
__device__ __forceinline__ float tanhf_(float x) {
    float e = __expf(2.0f * x);
    return 1.0f - 2.0f / (e + 1.0f);
}
__device__ __forceinline__ float seluf_(float x) {
    const float a = 1.6732632423543772f, s = 1.0507009873554805f;
    return x > 0.0f ? s * x : s * a * (__expf(x) - 1.0f);
}
__device__ __forceinline__ float erfinvf_(float x) {
    float w = -log1pf(-x * x);
    float p;
    if (w < 5.0f) {
        w -= 2.5f;
        p = 2.81022636e-08f;
        p = fmaf(p, w, 3.43273939e-07f);
        p = fmaf(p, w, -3.5233877e-06f);
        p = fmaf(p, w, -4.39150654e-06f);
        p = fmaf(p, w, 0.00021858087f);
        p = fmaf(p, w, -0.00125372503f);
        p = fmaf(p, w, -0.00417768164f);
        p = fmaf(p, w, 0.246640727f);
        p = fmaf(p, w, 1.50140941f);
    } else {
        w = sqrtf(w) - 3.0f;
        p = -0.000200214257f;
        p = fmaf(p, w, 0.000100950558f);
        p = fmaf(p, w, 0.00134934322f);
        p = fmaf(p, w, -0.00367342844f);
        p = fmaf(p, w, 0.00573950773f);
        p = fmaf(p, w, -0.0076224613f);
        p = fmaf(p, w, 0.00943887047f);
        p = fmaf(p, w, 1.00167406f);
        p = fmaf(p, w, 2.83297682f);
    }
    return p * x;
}

#define TF_ROUND(x0, x1, R) { x0 += x1; x1 = (x1 << (R)) | (x1 >> (32 - (R))); x1 ^= x0; }

__device__ __forceinline__ void threefry_(unsigned c0, unsigned c1, unsigned& r0, unsigned& r1) {
    const unsigned ks0 = 0u, ks1 = 42u, ks2 = 0x1BD11BDAu ^ 0u ^ 42u;
    unsigned x0 = c0 + ks0, x1 = c1 + ks1;
    TF_ROUND(x0,x1,13) TF_ROUND(x0,x1,15) TF_ROUND(x0,x1,26) TF_ROUND(x0,x1,6)
    x0 += ks1; x1 += ks2 + 1u;
    TF_ROUND(x0,x1,17) TF_ROUND(x0,x1,29) TF_ROUND(x0,x1,16) TF_ROUND(x0,x1,24)
    x0 += ks2; x1 += ks0 + 2u;
    TF_ROUND(x0,x1,13) TF_ROUND(x0,x1,15) TF_ROUND(x0,x1,26) TF_ROUND(x0,x1,6)
    x0 += ks0; x1 += ks1 + 3u;
    TF_ROUND(x0,x1,17) TF_ROUND(x0,x1,29) TF_ROUND(x0,x1,16) TF_ROUND(x0,x1,24)
    x0 += ks1; x1 += ks2 + 4u;
    TF_ROUND(x0,x1,13) TF_ROUND(x0,x1,15) TF_ROUND(x0,x1,26) TF_ROUND(x0,x1,6)
    x0 += ks2; x1 += ks0 + 5u;
    r0 = x0; r1 = x1;
}

// eps[i]: bits = o0 ^ o1 of threefry2x32(key(0,42), (0, i))  [verified round 5]
__device__ __forceinline__ float jax_normal_(unsigned i) {
    unsigned o0, o1;
    threefry_(0u, i, o0, o1);
    unsigned bits = o0 ^ o1;
    unsigned fb = (bits >> 9) | 0x3F800000u;
    float f = __uint_as_float(fb) - 1.0f;
    const float lo = -0.99999994f;
    float u = f * 2.0f + lo;
    u = fmaxf(lo, u);
    return 1.41421356237f * erfinvf_(u);
}

typedef const float (*cmat)[HD];

// ---------------- quad-coop, k-QUARTER-split 256x256 matmul ----------------
// W [256+ out][256 k] as float4 [out][64]. Thread (kh=tid>>8, t8=tid&255):
// oj=t8>>2, s=t8&3, output jj = oj+64*s. k-quarter kh (64 floats = 16 float4);
// quad lanes s read 4 CONSECUTIVE float4s per row per g (64B, coalesced, same as
// round 10). In-reads: 4 unique addresses per wave -> broadcast, conflict-free.
// 2-step quad butterfly -> quarter sums; cross-quarter combine via double-buffered
// part[pb][kh][r][t8] (lane-linear, conflict-free), ONE barrier. Each W element
// read exactly once per block. Returns full-k dots for owned rows kh*2, kh*2+1.
__device__ __forceinline__ void qmm(const float4* __restrict__ W4, cmat in,
                                    float& r0, float& r1,
                                    const int oj, const int s, const int kh, const int t8,
                                    float (*__restrict__ part)[4][RB][256], const int pb)
{
    float a0[RB], a1[RB], a2[RB], a3[RB];
#pragma unroll
    for (int r = 0; r < RB; ++r) { a0[r] = 0.f; a1[r] = 0.f; a2[r] = 0.f; a3[r] = 0.f; }
    const float4* wp = W4 + (size_t)oj * 64 + kh * 16 + s;
#pragma unroll 2
    for (int g = 0; g < 4; ++g) {
        const float4 w0 = wp[g * 4];
        const float4 w1 = wp[g * 4 + 4096];    // +64 rows
        const float4 w2 = wp[g * 4 + 8192];    // +128 rows
        const float4 w3 = wp[g * 4 + 12288];   // +192 rows
        const int ko = kh * 64 + g * 16 + s * 4;
#pragma unroll
        for (int r = 0; r < RB; ++r) {
            const float4 av = *(const float4*)(&in[r][ko]);
            a0[r] = fmaf(av.w, w0.w, fmaf(av.z, w0.z, fmaf(av.y, w0.y, fmaf(av.x, w0.x, a0[r]))));
            a1[r] = fmaf(av.w, w1.w, fmaf(av.z, w1.z, fmaf(av.y, w1.y, fmaf(av.x, w1.x, a1[r]))));
            a2[r] = fmaf(av.w, w2.w, fmaf(av.z, w2.z, fmaf(av.y, w2.y, fmaf(av.x, w2.x, a2[r]))));
            a3[r] = fmaf(av.w, w3.w, fmaf(av.z, w3.z, fmaf(av.y, w3.y, fmaf(av.x, w3.x, a3[r]))));
        }
    }
    // 2-step quad butterfly (sums the 4 k-chunks within this quarter)
    float mine[RB];
#pragma unroll
    for (int r = 0; r < RB; ++r) {
        float v0 = a0[r]; v0 += __shfl_xor(v0, 1); v0 += __shfl_xor(v0, 2);
        float v1 = a1[r]; v1 += __shfl_xor(v1, 1); v1 += __shfl_xor(v1, 2);
        float v2 = a2[r]; v2 += __shfl_xor(v2, 1); v2 += __shfl_xor(v2, 2);
        float v3 = a3[r]; v3 += __shfl_xor(v3, 1); v3 += __shfl_xor(v3, 2);
        mine[r] = (s == 0) ? v0 : (s == 1) ? v1 : (s == 2) ? v2 : v3;
    }
    const int R0 = kh * 2, R1 = R0 + 1;
    // publish partials for the 6 rows owned by other quarters
#pragma unroll
    for (int r = 0; r < RB; ++r) {
        if (r != R0 && r != R1) part[pb][kh][r][t8] = mine[r];
    }
    __syncthreads();
    // gather the other 3 quarters' partials for our 2 rows
    float s0 = mine[R0], s1 = mine[R1];
#pragma unroll
    for (int q = 1; q < 4; ++q) {
        const int qq = (kh + q) & 3;
        s0 += part[pb][qq][R0][t8];
        s1 += part[pb][qq][R1][t8];
    }
    r0 = s0; r1 = s1;
}

// ---------------- fused pipeline kernel ----------------
__global__ __launch_bounds__(TB) void fused_kernel(
    const float* __restrict__ x,      // [2048][64][4]
    const float* __restrict__ meta,   // [2048][4]
    const float* __restrict__ W_ih,   // [768][8]
    const float* __restrict__ W_hh,   // [768][256]
    const float* __restrict__ b_ih,   // [768]
    const float* __restrict__ b_hh,   // [768]
    const float* __restrict__ eW1,    // [256][256]
    const float* __restrict__ eb1,    // [256]
    const float* __restrict__ eW2,    // [512][256]
    const float* __restrict__ eb2,    // [512]
    const float* __restrict__ oW1, const float* __restrict__ ob1,
    const float* __restrict__ oW2, const float* __restrict__ ob2,
    const float* __restrict__ oW3, const float* __restrict__ ob3,
    const float* __restrict__ oW4, const float* __restrict__ ob4,
    const float* __restrict__ outW,   // [260]
    const float* __restrict__ outb,   // [1]
    float* __restrict__ out)          // [2048]
{
    const int tid = threadIdx.x;
    const int kh  = tid >> 8;            // k-quarter; owns rows kh*2, kh*2+1
    const int t8  = tid & 255;
    const int oj  = t8 >> 2;
    const int s   = t8 & 3;
    const int jj  = oj + 64 * s;         // owned output column
    const int R0  = kh * 2, R1 = R0 + 1; // owned rows
    const int b0  = blockIdx.x * RB;

    __shared__ float h0[RB][HD];
    __shared__ float h1[RB][HD];
    __shared__ float tA[RB][HD];
    __shared__ float tB[RB][HD];
    __shared__ float ytmp[RB][HD];
    __shared__ float xall[RB][TT * 4];
    __shared__ float part[2][4][RB][256];   // 64 KB partial exchange (double-buffered)
    __shared__ float meta_s[RB][4];
    __shared__ float dt_s[RB];
    __shared__ float red[TB];
    // ~116 KB LDS -> 1 block/CU, 16 waves = 4/SIMD

    const float4* Whh4 = (const float4*)W_hh;
    const float4* E1f4 = (const float4*)eW1;
    const float4* E2f4 = (const float4*)eW2;
    const float4* O1f4 = (const float4*)oW1;
    const float4* O2f4 = (const float4*)oW2;
    const float4* O3f4 = (const float4*)oW3;
    const float4* O4f4 = (const float4*)oW4;

    cmat tAc = (cmat)tA, tBc = (cmat)tB, ytc = (cmat)ytmp;

    int pb = 0;
    auto QMM = [&](const float4* W4p, cmat inp, float& q0, float& q1) {
        qmm(W4p, inp, q0, q1, oj, s, kh, t8, part, pb);
        pb ^= 1;
    };

    // ---- stage x, meta; zero h0 ----
#pragma unroll
    for (int i = 0; i < 2; ++i) {
        int idx = tid + i * TB;
        int r = idx >> 8, c = idx & 255;
        xall[r][c] = x[(size_t)(b0 + r) * 256 + c];
    }
    if (tid < RB * 4) { int r = tid >> 2, mm = tid & 3; meta_s[r][mm] = meta[(b0 + r) * 4 + mm]; }
    if (tid < 2 * HD) { int r = tid >> 8, c = tid & 255;
        h0[r][c] = 0.0f; h0[r + 2][c] = 0.0f; h0[r + 4][c] = 0.0f; h0[r + 6][c] = 0.0f; }
    __syncthreads();
    if (tid < RB) dt_s[tid] = (xall[tid][TT * 4 - 4] - xall[tid][0]) * (1.0f / (float)NST);

    // ---- GRU per-lane x-side constants for owned output jj ----
    float wir[4], wiz[4], win[4];
#pragma unroll
    for (int d = 0; d < 4; ++d) {
        wir[d] = W_ih[(size_t)jj * 8 + d];
        wiz[d] = W_ih[(size_t)(jj + 256) * 8 + d];
        win[d] = W_ih[(size_t)(jj + 512) * 8 + d];
    }
    float base_r[2], base_z[2], base_xn[2];
    {
        float mwr[4], mwz[4], mwn[4];
#pragma unroll
        for (int mm = 0; mm < 4; ++mm) {
            mwr[mm] = W_ih[(size_t)jj * 8 + 4 + mm];
            mwz[mm] = W_ih[(size_t)(jj + 256) * 8 + 4 + mm];
            mwn[mm] = W_ih[(size_t)(jj + 512) * 8 + 4 + mm];
        }
        const float bir = b_ih[jj], biz = b_ih[jj + 256], bin_ = b_ih[jj + 512];
        const float bhr = b_hh[jj], bhz = b_hh[jj + 256];
#pragma unroll
        for (int r = 0; r < 2; ++r) {
            const int R = R0 + r;
            float sr = bir + bhr, sz = biz + bhz, sn = bin_;
#pragma unroll
            for (int mm = 0; mm < 4; ++mm) {
                float mv = meta_s[R][mm];
                sr = fmaf(mv, mwr[mm], sr);
                sz = fmaf(mv, mwz[mm], sz);
                sn = fmaf(mv, mwn[mm], sn);
            }
            base_r[r] = sr; base_z[r] = sz; base_xn[r] = sn;
        }
    }
    const float bhn = b_hh[512 + jj];

    // ---- GRU: 64 steps, ping-pong h0/h1 ----
    float (*hc)[HD] = h0;
    float (*hn)[HD] = h1;
#pragma unroll 1
    for (int t = 0; t < TT; ++t) {
        float aR0, aR1, aZ0, aZ1, aN0, aN1;
        QMM(Whh4,         (cmat)hc, aR0, aR1);
        QMM(Whh4 + 16384, (cmat)hc, aZ0, aZ1);
        QMM(Whh4 + 32768, (cmat)hc, aN0, aN1);
#pragma unroll
        for (int r = 0; r < 2; ++r) {
            const int R = R0 + r;
            float xr = base_r[r], xz = base_z[r], xn = base_xn[r];
#pragma unroll
            for (int d = 0; d < 4; ++d) {
                float xv = xall[R][t * 4 + d];
                xr = fmaf(xv, wir[d], xr);
                xz = fmaf(xv, wiz[d], xz);
                xn = fmaf(xv, win[d], xn);
            }
            float aRv = r ? aR1 : aR0, aZv = r ? aZ1 : aZ0, aNv = r ? aN1 : aN0;
            float rg = sigmoidf_(xr + aRv);
            float zg = sigmoidf_(xz + aZv);
            float ng = tanhf_(fmaf(rg, bhn + aNv, xn));
            float hp = hc[R][jj];
            hn[R][jj] = fmaf(zg, hp - ng, ng);
        }
        __syncthreads();
        float (*tmp)[HD] = hc; hc = hn; hn = tmp;
    }
    // final h in h0 (even swaps)

    // ---- encoder + sample y0 into h0 ----
    {
        float a0, a1;
        QMM(E1f4, (cmat)h0, a0, a1);
        const float eb1j = eb1[jj];
        tA[R0][jj] = fmaxf(a0 + eb1j, 0.0f);
        tA[R1][jj] = fmaxf(a1 + eb1j, 0.0f);
        __syncthreads();

        float aM0, aM1, aS0, aS1;
        QMM(E2f4,            tAc, aM0, aM1);
        QMM(E2f4 + 256 * 64, tAc, aS0, aS1);
        const float bm = eb2[jj], bs = eb2[256 + jj];
        float e0 = jax_normal_((unsigned)((b0 + R0) * HD + jj));
        float e1 = jax_normal_((unsigned)((b0 + R1) * HD + jj));
        h0[R0][jj] = fmaf(e0, aS0 + bs, aM0 + bm);
        h0[R1][jj] = fmaf(e1, aS1 + bs, aM1 + bm);
        __syncthreads();
    }

    // ---- dopri5 ----
    const float A21 = (float)(1.0/5.0);
    const float A31 = (float)(3.0/40.0),      A32 = (float)(9.0/40.0);
    const float A41 = (float)(44.0/45.0),     A42 = (float)(-56.0/15.0),    A43 = (float)(32.0/9.0);
    const float A51 = (float)(19372.0/6561.0),A52 = (float)(-25360.0/2187.0),
                A53 = (float)(64448.0/6561.0),A54 = (float)(-212.0/729.0);
    const float A61 = (float)(9017.0/3168.0), A62 = (float)(-355.0/33.0),
                A63 = (float)(46732.0/5247.0),A64 = (float)(49.0/176.0),    A65 = (float)(-5103.0/18656.0);
    const float B1f = (float)(35.0/384.0),    B3f = (float)(500.0/1113.0),  B4f = (float)(125.0/192.0),
                B5f = (float)(-2187.0/6784.0),B6f = (float)(11.0/84.0);

    const float ob1j = ob1[jj], ob2j = ob2[jj], ob3j = ob3[jj], ob4j = ob4[jj];
    const float dt0 = dt_s[R0], dt1 = dt_s[R1];
    float k1[2], k2[2], k3[2], k4[2], k5[2], k6[2];

#pragma unroll 1
    for (int st = 0; st < NST; ++st) {
#pragma unroll 1
        for (int stage = 0; stage < 6; ++stage) {
            cmat yin = (stage == 0) ? (cmat)h0 : ytc;
            float a0, a1;
            QMM(O1f4, yin, a0, a1);
            tA[R0][jj] = seluf_(a0 + ob1j);
            tA[R1][jj] = seluf_(a1 + ob1j);
            __syncthreads();
            QMM(O2f4, tAc, a0, a1);
            tB[R0][jj] = seluf_(a0 + ob2j);
            tB[R1][jj] = seluf_(a1 + ob2j);
            __syncthreads();
            QMM(O3f4, tBc, a0, a1);
            tA[R0][jj] = seluf_(a0 + ob3j);
            tA[R1][jj] = seluf_(a1 + ob3j);
            __syncthreads();
            QMM(O4f4, tAc, a0, a1);

            switch (stage) {
            case 0:
                k1[0] = a0 + ob4j; k1[1] = a1 + ob4j;
                ytmp[R0][jj] = fmaf(dt0, A21 * k1[0], h0[R0][jj]);
                ytmp[R1][jj] = fmaf(dt1, A21 * k1[1], h0[R1][jj]);
                break;
            case 1:
                k2[0] = a0 + ob4j; k2[1] = a1 + ob4j;
                ytmp[R0][jj] = fmaf(dt0, fmaf(A32, k2[0], A31 * k1[0]), h0[R0][jj]);
                ytmp[R1][jj] = fmaf(dt1, fmaf(A32, k2[1], A31 * k1[1]), h0[R1][jj]);
                break;
            case 2:
                k3[0] = a0 + ob4j; k3[1] = a1 + ob4j;
                ytmp[R0][jj] = fmaf(dt0, fmaf(A43, k3[0], fmaf(A42, k2[0], A41 * k1[0])), h0[R0][jj]);
                ytmp[R1][jj] = fmaf(dt1, fmaf(A43, k3[1], fmaf(A42, k2[1], A41 * k1[1])), h0[R1][jj]);
                break;
            case 3:
                k4[0] = a0 + ob4j; k4[1] = a1 + ob4j;
                ytmp[R0][jj] = fmaf(dt0, fmaf(A54, k4[0], fmaf(A53, k3[0], fmaf(A52, k2[0], A51 * k1[0]))), h0[R0][jj]);
                ytmp[R1][jj] = fmaf(dt1, fmaf(A54, k4[1], fmaf(A53, k3[1], fmaf(A52, k2[1], A51 * k1[1]))), h0[R1][jj]);
                break;
            case 4:
                k5[0] = a0 + ob4j; k5[1] = a1 + ob4j;
                ytmp[R0][jj] = fmaf(dt0, fmaf(A65, k5[0], fmaf(A64, k4[0],
                               fmaf(A63, k3[0], fmaf(A62, k2[0], A61 * k1[0])))), h0[R0][jj]);
                ytmp[R1][jj] = fmaf(dt1, fmaf(A65, k5[1], fmaf(A64, k4[1],
                               fmaf(A63, k3[1], fmaf(A62, k2[1], A61 * k1[1])))), h0[R1][jj]);
                break;
            default:
                k6[0] = a0 + ob4j; k6[1] = a1 + ob4j;
                h0[R0][jj] = fmaf(dt0, fmaf(B6f, k6[0], fmaf(B5f, k5[0],
                             fmaf(B4f, k4[0], fmaf(B3f, k3[0], B1f * k1[0])))), h0[R0][jj]);
                h0[R1][jj] = fmaf(dt1, fmaf(B6f, k6[1], fmaf(B5f, k5[1],
                             fmaf(B4f, k4[1], fmaf(B3f, k3[1], B1f * k1[1])))), h0[R1][jj]);
                break;
            }
            __syncthreads();
        }
    }

    // ---- output head: 4 rows per pass ----
#pragma unroll 1
    for (int rp4 = 0; rp4 < 2; ++rp4) {
        const int R = rp4 * 4 + (tid >> 8);
        red[tid] = h0[R][t8] * outW[t8];
        __syncthreads();
        for (int sw = 128; sw > 0; sw >>= 1) {
            if (t8 < sw) red[tid] += red[tid + sw];
            __syncthreads();
        }
        if (t8 == 0) {
            float acc = red[tid] + outb[0];
#pragma unroll
            for (int mm = 0; mm < 4; ++mm) acc = fmaf(meta_s[R][mm], outW[HD + mm], acc);
            out[b0 + R] = acc;
        }
        __syncthreads();
    }
}

extern "C" void kernel_launch(void* const* d_in, const int* in_sizes, int n_in,
                              void* d_out, int out_size, void* d_ws, size_t ws_size,
                              hipStream_t stream) {
    const float* x    = (const float*)d_in[0];
    const float* meta = (const float*)d_in[1];
    const float* W_ih = (const float*)d_in[2];
    const float* W_hh = (const float*)d_in[3];
    const float* b_ih = (const float*)d_in[4];
    const float* b_hh = (const float*)d_in[5];
    const float* eW1  = (const float*)d_in[6];
    const float* eb1  = (const float*)d_in[7];
    const float* eW2  = (const float*)d_in[8];
    const float* eb2  = (const float*)d_in[9];
    const float* oW1  = (const float*)d_in[10];
    const float* ob1  = (const float*)d_in[11];
    const float* oW2  = (const float*)d_in[12];
    const float* ob2  = (const float*)d_in[13];
    const float* oW3  = (const float*)d_in[14];
    const float* ob3  = (const float*)d_in[15];
    const float* oW4  = (const float*)d_in[16];
    const float* ob4  = (const float*)d_in[17];
    const float* outW = (const float*)d_in[18];
    const float* outb = (const float*)d_in[19];

    fused_kernel<<<BSZ / RB, TB, 0, stream>>>(x, meta, W_ih, W_hh, b_ih, b_hh,
                                              eW1, eb1, eW2, eb2,
                                              oW1, ob1, oW2, ob2, oW3, ob3, oW4, ob4,
                                              outW, outb, (float*)d_out);
}

// Round 13
// 3298.340 us; speedup vs baseline: 2.3659x; 1.7897x over previous
//
#include <hip/hip_runtime.h>
#include <math.h>

#define HD   256
#define RB   8      // batch rows per block -> grid 256 = 1 block/CU
#define TB   1024   // 16 waves, 4/SIMD
#define TT   64
#define NST  32
#define BSZ  2048

typedef __attribute__((ext_vector_type(8))) short short8;
typedef __attribute__((ext_vector_type(4))) float f32x4;
typedef unsigned short ushort_t;

// ---------------- math helpers ----------------
__device__ __forceinline__ float sigmoidf_(float x) {
    return 1.0f / (1.0f + __expf(-x));
}
__device__ __forceinline__ float tanhf_(float x) {
    float e = __expf(2.0f * x);
    return 1.0f - 2.0f / (e + 1.0f);
}
__device__ __forceinline__ float seluf_(float x) {
    const float a = 1.6732632423543772f, s = 1.0507009873554805f;
    return x > 0.0f ? s * x : s * a * (__expf(x) - 1.0f);
}
__device__ __forceinline__ float erfinvf_(float x) {
    float w = -log1pf(-x * x);
    float p;
    if (w < 5.0f) {
        w -= 2.5f;
        p = 2.81022636e-08f;
        p = fmaf(p, w, 3.43273939e-07f);
        p = fmaf(p, w, -3.5233877e-06f);
        p = fmaf(p, w, -4.39150654e-06f);
        p = fmaf(p, w, 0.00021858087f);
        p = fmaf(p, w, -0.00125372503f);
        p = fmaf(p, w, -0.00417768164f);
        p = fmaf(p, w, 0.246640727f);
        p = fmaf(p, w, 1.50140941f);
    } else {
        w = sqrtf(w) - 3.0f;
        p = -0.000200214257f;
        p = fmaf(p, w, 0.000100950558f);
        p = fmaf(p, w, 0.00134934322f);
        p = fmaf(p, w, -0.00367342844f);
        p = fmaf(p, w, 0.00573950773f);
        p = fmaf(p, w, -0.0076224613f);
        p = fmaf(p, w, 0.00943887047f);
        p = fmaf(p, w, 1.00167406f);
        p = fmaf(p, w, 2.83297682f);
    }
    return p * x;
}

#define TF_ROUND(x0, x1, R) { x0 += x1; x1 = (x1 << (R)) | (x1 >> (32 - (R))); x1 ^= x0; }

__device__ __forceinline__ void threefry_(unsigned c0, unsigned c1, unsigned& r0, unsigned& r1) {
    const unsigned ks0 = 0u, ks1 = 42u, ks2 = 0x1BD11BDAu ^ 0u ^ 42u;
    unsigned x0 = c0 + ks0, x1 = c1 + ks1;
    TF_ROUND(x0,x1,13) TF_ROUND(x0,x1,15) TF_ROUND(x0,x1,26) TF_ROUND(x0,x1,6)
    x0 += ks1; x1 += ks2 + 1u;
    TF_ROUND(x0,x1,17) TF_ROUND(x0,x1,29) TF_ROUND(x0,x1,16) TF_ROUND(x0,x1,24)
    x0 += ks2; x1 += ks0 + 2u;
    TF_ROUND(x0,x1,13) TF_ROUND(x0,x1,15) TF_ROUND(x0,x1,26) TF_ROUND(x0,x1,6)
    x0 += ks0; x1 += ks1 + 3u;
    TF_ROUND(x0,x1,17) TF_ROUND(x0,x1,29) TF_ROUND(x0,x1,16) TF_ROUND(x0,x1,24)
    x0 += ks1; x1 += ks2 + 4u;
    TF_ROUND(x0,x1,13) TF_ROUND(x0,x1,15) TF_ROUND(x0,x1,26) TF_ROUND(x0,x1,6)
    x0 += ks2; x1 += ks0 + 5u;
    r0 = x0; r1 = x1;
}

// eps[i]: bits = o0 ^ o1 of threefry2x32(key(0,42), (0, i))  [verified round 5]
__device__ __forceinline__ float jax_normal_(unsigned i) {
    unsigned o0, o1;
    threefry_(0u, i, o0, o1);
    unsigned bits = o0 ^ o1;
    unsigned fb = (bits >> 9) | 0x3F800000u;
    float f = __uint_as_float(fb) - 1.0f;
    const float lo = -0.99999994f;
    float u = f * 2.0f + lo;
    u = fmaxf(lo, u);
    return 1.41421356237f * erfinvf_(u);
}

// fp32 -> bf16 RNE
__device__ __forceinline__ ushort_t f2bf(float f) {
    unsigned u = __float_as_uint(f);
    return (ushort_t)((u + 0x7FFFu + ((u >> 16) & 1u)) >> 16);
}

// swizzled bf16 mirror index (ushort units): row stride 256, 16B-chunk XOR swizzle
__device__ __forceinline__ int midx(int row, int k) {
    int chunk = k >> 3;
    return row * 256 + (((chunk ^ (row & 7)) << 3) | (k & 7));
}

typedef const float (*cmat)[HD];

// ---------------- fp32 quad-coop k-quarter qmm (GRU/encoder; verified R12) ----------------
__device__ __forceinline__ void qmm(const float4* __restrict__ W4, cmat in,
                                    float& r0, float& r1,
                                    const int oj, const int s, const int kh, const int t8,
                                    float (*__restrict__ part)[4][RB][256], const int pb)
{
    float a0[RB], a1[RB], a2[RB], a3[RB];
#pragma unroll
    for (int r = 0; r < RB; ++r) { a0[r] = 0.f; a1[r] = 0.f; a2[r] = 0.f; a3[r] = 0.f; }
    const float4* wp = W4 + (size_t)oj * 64 + kh * 16 + s;
#pragma unroll 2
    for (int g = 0; g < 4; ++g) {
        const float4 w0 = wp[g * 4];
        const float4 w1 = wp[g * 4 + 4096];
        const float4 w2 = wp[g * 4 + 8192];
        const float4 w3 = wp[g * 4 + 12288];
        const int ko = kh * 64 + g * 16 + s * 4;
#pragma unroll
        for (int r = 0; r < RB; ++r) {
            const float4 av = *(const float4*)(&in[r][ko]);
            a0[r] = fmaf(av.w, w0.w, fmaf(av.z, w0.z, fmaf(av.y, w0.y, fmaf(av.x, w0.x, a0[r]))));
            a1[r] = fmaf(av.w, w1.w, fmaf(av.z, w1.z, fmaf(av.y, w1.y, fmaf(av.x, w1.x, a1[r]))));
            a2[r] = fmaf(av.w, w2.w, fmaf(av.z, w2.z, fmaf(av.y, w2.y, fmaf(av.x, w2.x, a2[r]))));
            a3[r] = fmaf(av.w, w3.w, fmaf(av.z, w3.z, fmaf(av.y, w3.y, fmaf(av.x, w3.x, a3[r]))));
        }
    }
    float mine[RB];
#pragma unroll
    for (int r = 0; r < RB; ++r) {
        float v0 = a0[r]; v0 += __shfl_xor(v0, 1); v0 += __shfl_xor(v0, 2);
        float v1 = a1[r]; v1 += __shfl_xor(v1, 1); v1 += __shfl_xor(v1, 2);
        float v2 = a2[r]; v2 += __shfl_xor(v2, 1); v2 += __shfl_xor(v2, 2);
        float v3 = a3[r]; v3 += __shfl_xor(v3, 1); v3 += __shfl_xor(v3, 2);
        mine[r] = (s == 0) ? v0 : (s == 1) ? v1 : (s == 2) ? v2 : v3;
    }
    const int R0 = kh * 2, R1 = R0 + 1;
#pragma unroll
    for (int r = 0; r < RB; ++r) {
        if (r != R0 && r != R1) part[pb][kh][r][t8] = mine[r];
    }
    __syncthreads();
    float s0 = mine[R0], s1 = mine[R1];
#pragma unroll
    for (int q = 1; q < 4; ++q) {
        const int qq = (kh + q) & 3;
        s0 += part[pb][qq][R0][t8];
        s1 += part[pb][qq][R1][t8];
    }
    r0 = s0; r1 = s1;
}

// ---------------- MFMA 256->256 bf16 layer (ODE) ----------------
// A: activations from swizzled bf16 mirror, rows 0-7 real / 8-15 zero pad.
// B: weights bf16 (ws blob) or fp32->bf16 on the fly. Lane: m/n = l&15, kb = l>>4.
// Accumulate K=256 over 8 MFMAs. D: col=lane&15, row=(lane>>4)*4+reg [verified m89].
template<int WBF>
__device__ __forceinline__ f32x4 mfma_layer(const ushort_t* __restrict__ inbf,
                                            const ushort_t* __restrict__ Wbf,
                                            const float* __restrict__ Wf,
                                            const int lm, const int kb, const int jo)
{
    f32x4 acc = {0.f, 0.f, 0.f, 0.f};
#pragma unroll
    for (int kt = 0; kt < 8; ++kt) {
        const int k0 = kt * 32 + kb * 8;
        short8 a = *(const short8*)(inbf + midx(lm, k0));
        short8 b;
        if (WBF) {
            b = *(const short8*)(Wbf + (size_t)jo * 256 + k0);
        } else {
            const float4 w0 = *(const float4*)(Wf + (size_t)jo * 256 + k0);
            const float4 w1 = *(const float4*)(Wf + (size_t)jo * 256 + k0 + 4);
            union { ushort_t u[8]; short8 v; } bb;
            bb.u[0] = f2bf(w0.x); bb.u[1] = f2bf(w0.y); bb.u[2] = f2bf(w0.z); bb.u[3] = f2bf(w0.w);
            bb.u[4] = f2bf(w1.x); bb.u[5] = f2bf(w1.y); bb.u[6] = f2bf(w1.z); bb.u[7] = f2bf(w1.w);
            b = bb.v;
        }
        acc = __builtin_amdgcn_mfma_f32_16x16x32_bf16(a, b, acc, 0, 0, 0);
    }
    return acc;
}

// ---------------- weight bf16 conversion prepass (into d_ws; bounds-checked on host) ----------------
__global__ void cvt_k(const float* __restrict__ a, const float* __restrict__ b,
                      const float* __restrict__ c, const float* __restrict__ d,
                      ushort_t* __restrict__ o) {
    int i = blockIdx.x * blockDim.x + threadIdx.x;    // 0..262143
    int m = i >> 16, r = i & 65535;
    const float* src = (m == 0) ? a : (m == 1) ? b : (m == 2) ? c : d;
    o[i] = f2bf(src[r]);
}

// ---------------- fused pipeline kernel ----------------
template<int WBF>
__global__ __launch_bounds__(TB) void fused_kernel(
    const float* __restrict__ x,
    const float* __restrict__ meta,
    const float* __restrict__ W_ih,
    const float* __restrict__ W_hh,
    const float* __restrict__ b_ih,
    const float* __restrict__ b_hh,
    const float* __restrict__ eW1,
    const float* __restrict__ eb1,
    const float* __restrict__ eW2,
    const float* __restrict__ eb2,
    const float* __restrict__ oW1, const float* __restrict__ ob1,
    const float* __restrict__ oW2, const float* __restrict__ ob2,
    const float* __restrict__ oW3, const float* __restrict__ ob3,
    const float* __restrict__ oW4, const float* __restrict__ ob4,
    const float* __restrict__ outW,
    const float* __restrict__ outb,
    const ushort_t* __restrict__ wsbf,   // [4][256][256] bf16 (WBF=1)
    float* __restrict__ out)
{
    const int tid = threadIdx.x;
    // fp32-qmm mapping (GRU/encoder)
    const int kh  = tid >> 8;
    const int t8  = tid & 255;
    const int oj  = t8 >> 2;
    const int s   = t8 & 3;
    const int jj  = oj + 64 * s;
    const int R0  = kh * 2, R1 = R0 + 1;
    // MFMA mapping (ODE)
    const int l   = tid & 63;
    const int w   = tid >> 6;            // wave / N-tile
    const int lm  = l & 15;              // A row / B col
    const int kb  = l >> 4;              // k-block
    const int jo  = w * 16 + lm;         // owned output col
    const int er  = l >> 4;              // epilogue row group (lanes<32: rows er*4+r)
    const bool act = (l < 32);
    const int b0  = blockIdx.x * RB;

    __shared__ float h0[RB][HD];
    __shared__ float h1[RB][HD];
    __shared__ float tA[RB][HD];
    __shared__ float xall[RB][TT * 4];
    __shared__ float part[2][4][RB][256];
    __shared__ float red[TB];
    __shared__ __align__(16) ushort_t mir[4][16][256];   // ybf, ytbf, t1bf, t2bf
    __shared__ float meta_s[RB][4];
    __shared__ float dt_s[RB];
    // ~132 KB LDS -> 1 block/CU, 16 waves = 4/SIMD

    const float4* Whh4 = (const float4*)W_hh;
    const float4* E1f4 = (const float4*)eW1;
    const float4* E2f4 = (const float4*)eW2;
    ushort_t* YBF = &mir[0][0][0];
    ushort_t* YTB = &mir[1][0][0];
    ushort_t* T1B = &mir[2][0][0];
    ushort_t* T2B = &mir[3][0][0];
    const ushort_t* wsO1 = wsbf;
    const ushort_t* wsO2 = wsbf + 65536;
    const ushort_t* wsO3 = wsbf + 131072;
    const ushort_t* wsO4 = wsbf + 196608;

    cmat tAc = (cmat)tA;

    int pb = 0;
    auto QMM = [&](const float4* W4p, cmat inp, float& q0, float& q1) {
        qmm(W4p, inp, q0, q1, oj, s, kh, t8, part, pb);
        pb ^= 1;
    };

    // ---- stage x, meta; zero h0 and bf16 mirrors ----
#pragma unroll
    for (int i = 0; i < 2; ++i) {
        int idx = tid + i * TB;
        int r = idx >> 8, c = idx & 255;
        xall[r][c] = x[(size_t)(b0 + r) * 256 + c];
    }
    if (tid < RB * 4) { int r = tid >> 2, mm = tid & 3; meta_s[r][mm] = meta[(b0 + r) * 4 + mm]; }
    if (tid < 2 * HD) { int r = tid >> 8, c = tid & 255;
        h0[r][c] = 0.0f; h0[r + 2][c] = 0.0f; h0[r + 4][c] = 0.0f; h0[r + 6][c] = 0.0f; }
    {
        unsigned* mz = (unsigned*)&mir[0][0][0];   // 8192 u32
#pragma unroll
        for (int i = 0; i < 8; ++i) mz[tid + i * TB] = 0u;
    }
    __syncthreads();
    if (tid < RB) dt_s[tid] = (xall[tid][TT * 4 - 4] - xall[tid][0]) * (1.0f / (float)NST);

    // ---- GRU per-lane x-side constants ----
    float wir[4], wiz[4], win[4];
#pragma unroll
    for (int d = 0; d < 4; ++d) {
        wir[d] = W_ih[(size_t)jj * 8 + d];
        wiz[d] = W_ih[(size_t)(jj + 256) * 8 + d];
        win[d] = W_ih[(size_t)(jj + 512) * 8 + d];
    }
    float base_r[2], base_z[2], base_xn[2];
    {
        float mwr[4], mwz[4], mwn[4];
#pragma unroll
        for (int mm = 0; mm < 4; ++mm) {
            mwr[mm] = W_ih[(size_t)jj * 8 + 4 + mm];
            mwz[mm] = W_ih[(size_t)(jj + 256) * 8 + 4 + mm];
            mwn[mm] = W_ih[(size_t)(jj + 512) * 8 + 4 + mm];
        }
        const float bir = b_ih[jj], biz = b_ih[jj + 256], bin_ = b_ih[jj + 512];
        const float bhr = b_hh[jj], bhz = b_hh[jj + 256];
#pragma unroll
        for (int r = 0; r < 2; ++r) {
            const int R = R0 + r;
            float sr = bir + bhr, sz = biz + bhz, sn = bin_;
#pragma unroll
            for (int mm = 0; mm < 4; ++mm) {
                float mv = meta_s[R][mm];
                sr = fmaf(mv, mwr[mm], sr);
                sz = fmaf(mv, mwz[mm], sz);
                sn = fmaf(mv, mwn[mm], sn);
            }
            base_r[r] = sr; base_z[r] = sz; base_xn[r] = sn;
        }
    }
    const float bhn = b_hh[512 + jj];

    // ---- GRU: 64 steps (fp32, exact) ----
    float (*hc)[HD] = h0;
    float (*hn)[HD] = h1;
#pragma unroll 1
    for (int t = 0; t < TT; ++t) {
        float aR0, aR1, aZ0, aZ1, aN0, aN1;
        QMM(Whh4,         (cmat)hc, aR0, aR1);
        QMM(Whh4 + 16384, (cmat)hc, aZ0, aZ1);
        QMM(Whh4 + 32768, (cmat)hc, aN0, aN1);
#pragma unroll
        for (int r = 0; r < 2; ++r) {
            const int R = R0 + r;
            float xr = base_r[r], xz = base_z[r], xn = base_xn[r];
#pragma unroll
            for (int d = 0; d < 4; ++d) {
                float xv = xall[R][t * 4 + d];
                xr = fmaf(xv, wir[d], xr);
                xz = fmaf(xv, wiz[d], xz);
                xn = fmaf(xv, win[d], xn);
            }
            float aRv = r ? aR1 : aR0, aZv = r ? aZ1 : aZ0, aNv = r ? aN1 : aN0;
            float rg = sigmoidf_(xr + aRv);
            float zg = sigmoidf_(xz + aZv);
            float ng = tanhf_(fmaf(rg, bhn + aNv, xn));
            float hp = hc[R][jj];
            hn[R][jj] = fmaf(zg, hp - ng, ng);
        }
        __syncthreads();
        float (*tmp)[HD] = hc; hc = hn; hn = tmp;
    }

    // ---- encoder + sample y0 (fp32, exact) ----
    {
        float a0, a1;
        QMM(E1f4, (cmat)h0, a0, a1);
        const float eb1j = eb1[jj];
        tA[R0][jj] = fmaxf(a0 + eb1j, 0.0f);
        tA[R1][jj] = fmaxf(a1 + eb1j, 0.0f);
        __syncthreads();

        float aM0, aM1, aS0, aS1;
        QMM(E2f4,            tAc, aM0, aM1);
        QMM(E2f4 + 256 * 64, tAc, aS0, aS1);
        const float bm = eb2[jj], bs = eb2[256 + jj];
        float e0 = jax_normal_((unsigned)((b0 + R0) * HD + jj));
        float e1 = jax_normal_((unsigned)((b0 + R1) * HD + jj));
        float y0a = fmaf(e0, aS0 + bs, aM0 + bm);
        float y0b = fmaf(e1, aS1 + bs, aM1 + bm);
        h0[R0][jj] = y0a;
        h0[R1][jj] = y0b;
        YBF[midx(R0, jj)] = f2bf(y0a);
        YBF[midx(R1, jj)] = f2bf(y0b);
        __syncthreads();
    }

    // ---- dopri5: MFMA bf16 ODE ----
    const float A21 = (float)(1.0/5.0);
    const float A31 = (float)(3.0/40.0),      A32 = (float)(9.0/40.0);
    const float A41 = (float)(44.0/45.0),     A42 = (float)(-56.0/15.0),    A43 = (float)(32.0/9.0);
    const float A51 = (float)(19372.0/6561.0),A52 = (float)(-25360.0/2187.0),
                A53 = (float)(64448.0/6561.0),A54 = (float)(-212.0/729.0);
    const float A61 = (float)(9017.0/3168.0), A62 = (float)(-355.0/33.0),
                A63 = (float)(46732.0/5247.0),A64 = (float)(49.0/176.0),    A65 = (float)(-5103.0/18656.0);
    const float B1f = (float)(35.0/384.0),    B3f = (float)(500.0/1113.0),  B4f = (float)(125.0/192.0),
                B5f = (float)(-2187.0/6784.0),B6f = (float)(11.0/84.0);

    const float o1b = ob1[jo], o2b = ob2[jo], o3b = ob3[jo], o4b = ob4[jo];
    float dtv[4];
    if (act) {
#pragma unroll
        for (int r = 0; r < 4; ++r) dtv[r] = dt_s[er * 4 + r];
    }
    float k1[4], k2[4], k3[4], k4[4], k5[4], k6[4];

#pragma unroll 1
    for (int st = 0; st < NST; ++st) {
#pragma unroll 1
        for (int stage = 0; stage < 6; ++stage) {
            const ushort_t* in0 = (stage == 0) ? YBF : YTB;
            f32x4 acc = mfma_layer<WBF>(in0, wsO1, oW1, lm, kb, jo);
            if (act) {
#pragma unroll
                for (int r = 0; r < 4; ++r)
                    T1B[midx(er * 4 + r, jo)] = f2bf(seluf_(acc[r] + o1b));
            }
            __syncthreads();
            acc = mfma_layer<WBF>(T1B, wsO2, oW2, lm, kb, jo);
            if (act) {
#pragma unroll
                for (int r = 0; r < 4; ++r)
                    T2B[midx(er * 4 + r, jo)] = f2bf(seluf_(acc[r] + o2b));
            }
            __syncthreads();
            acc = mfma_layer<WBF>(T2B, wsO3, oW3, lm, kb, jo);
            if (act) {
#pragma unroll
                for (int r = 0; r < 4; ++r)
                    T1B[midx(er * 4 + r, jo)] = f2bf(seluf_(acc[r] + o3b));
            }
            __syncthreads();
            acc = mfma_layer<WBF>(T1B, wsO4, oW4, lm, kb, jo);
            if (act) {
#pragma unroll
                for (int r = 0; r < 4; ++r) {
                    const int row = er * 4 + r;
                    const float kc = acc[r] + o4b;
                    const float yv = h0[row][jo];
                    float sm;
                    switch (stage) {
                    case 0: k1[r] = kc; sm = A21 * kc; break;
                    case 1: k2[r] = kc; sm = fmaf(A32, kc, A31 * k1[r]); break;
                    case 2: k3[r] = kc; sm = fmaf(A43, kc, fmaf(A42, k2[r], A41 * k1[r])); break;
                    case 3: k4[r] = kc; sm = fmaf(A54, kc, fmaf(A53, k3[r], fmaf(A52, k2[r], A51 * k1[r]))); break;
                    case 4: k5[r] = kc; sm = fmaf(A65, kc, fmaf(A64, k4[r],
                                     fmaf(A63, k3[r], fmaf(A62, k2[r], A61 * k1[r])))); break;
                    default: k6[r] = kc; sm = fmaf(B6f, kc, fmaf(B5f, k5[r],
                                      fmaf(B4f, k4[r], fmaf(B3f, k3[r], B1f * k1[r])))); break;
                    }
                    const float yn = fmaf(dtv[r], sm, yv);
                    if (stage < 5) {
                        YTB[midx(row, jo)] = f2bf(yn);
                    } else {
                        h0[row][jo] = yn;
                        YBF[midx(row, jo)] = f2bf(yn);
                    }
                }
            }
            __syncthreads();
        }
    }

    // ---- output head ----
#pragma unroll 1
    for (int rp4 = 0; rp4 < 2; ++rp4) {
        const int R = rp4 * 4 + (tid >> 8);
        red[tid] = h0[R][t8] * outW[t8];
        __syncthreads();
        for (int sw = 128; sw > 0; sw >>= 1) {
            if (t8 < sw) red[tid] += red[tid + sw];
            __syncthreads();
        }
        if (t8 == 0) {
            float acc = red[tid] + outb[0];
#pragma unroll
            for (int mm = 0; mm < 4; ++mm) acc = fmaf(meta_s[R][mm], outW[HD + mm], acc);
            out[b0 + R] = acc;
        }
        __syncthreads();
    }
}

extern "C" void kernel_launch(void* const* d_in, const int* in_sizes, int n_in,
                              void* d_out, int out_size, void* d_ws, size_t ws_size,
                              hipStream_t stream) {
    const float* x    = (const float*)d_in[0];
    const float* meta = (const float*)d_in[1];
    const float* W_ih = (const float*)d_in[2];
    const float* W_hh = (const float*)d_in[3];
    const float* b_ih = (const float*)d_in[4];
    const float* b_hh = (const float*)d_in[5];
    const float* eW1  = (const float*)d_in[6];
    const float* eb1  = (const float*)d_in[7];
    const float* eW2  = (const float*)d_in[8];
    const float* eb2  = (const float*)d_in[9];
    const float* oW1  = (const float*)d_in[10];
    const float* ob1  = (const float*)d_in[11];
    const float* oW2  = (const float*)d_in[12];
    const float* ob2  = (const float*)d_in[13];
    const float* oW3  = (const float*)d_in[14];
    const float* ob3  = (const float*)d_in[15];
    const float* oW4  = (const float*)d_in[16];
    const float* ob4  = (const float*)d_in[17];
    const float* outW = (const float*)d_in[18];
    const float* outb = (const float*)d_in[19];

    const size_t need = (size_t)4 * 65536 * sizeof(ushort_t);   // 512 KB
    const bool wbf = (d_ws != nullptr) && (ws_size >= need);

    if (wbf) {
        cvt_k<<<1024, 256, 0, stream>>>(oW1, oW2, oW3, oW4, (ushort_t*)d_ws);
        fused_kernel<1><<<BSZ / RB, TB, 0, stream>>>(x, meta, W_ih, W_hh, b_ih, b_hh,
                                                     eW1, eb1, eW2, eb2,
                                                     oW1, ob1, oW2, ob2, oW3, ob3, oW4, ob4,
                                                     outW, outb, (const ushort_t*)d_ws,
                                                     (float*)d_out);
    } else {
        fused_kernel<0><<<BSZ / RB, TB, 0, stream>>>(x, meta, W_ih, W_hh, b_ih, b_hh,
                                                     eW1, eb1, eW2, eb2,
                                                     oW1, ob1, oW2, ob2, oW3, ob3, oW4, ob4,
                                                     outW, outb, (const ushort_t*)nullptr,
                                                     (float*)d_out);
    }
}

// Round 14
// 2726.566 us; speedup vs baseline: 2.8620x; 1.2097x over previous
//
#include <hip/hip_runtime.h>
#include <math.h>

#define HD   256
#define RB   8      // batch rows per block -> grid 256 = 1 block/CU
#define TB   1024   // 16 waves, 4/SIMD
#define TT   64
#define NST  32
#define BSZ  2048

typedef __attribute__((ext_vector_type(8))) short short8;
typedef __attribute__((ext_vector_type(4))) float f32x4;
typedef unsigned short ushort_t;

// ---------------- math helpers ----------------
__device__ __forceinline__ float sigmoidf_(float x) {
    return 1.0f / (1.0f + __expf(-x));
}
__device__ __forceinline__ float tanhf_(float x) {
    float e = __expf(2.0f * x);
    return 1.0f - 2.0f / (e + 1.0f);
}
__device__ __forceinline__ float seluf_(float x) {
    const float a = 1.6732632423543772f, s = 1.0507009873554805f;
    return x > 0.0f ? s * x : s * a * (__expf(x) - 1.0f);
}
__device__ __forceinline__ float erfinvf_(float x) {
    float w = -log1pf(-x * x);
    float p;
    if (w < 5.0f) {
        w -= 2.5f;
        p = 2.81022636e-08f;
        p = fmaf(p, w, 3.43273939e-07f);
        p = fmaf(p, w, -3.5233877e-06f);
        p = fmaf(p, w, -4.39150654e-06f);
        p = fmaf(p, w, 0.00021858087f);
        p = fmaf(p, w, -0.00125372503f);
        p = fmaf(p, w, -0.00417768164f);
        p = fmaf(p, w, 0.246640727f);
        p = fmaf(p, w, 1.50140941f);
    } else {
        w = sqrtf(w) - 3.0f;
        p = -0.000200214257f;
        p = fmaf(p, w, 0.000100950558f);
        p = fmaf(p, w, 0.00134934322f);
        p = fmaf(p, w, -0.00367342844f);
        p = fmaf(p, w, 0.00573950773f);
        p = fmaf(p, w, -0.0076224613f);
        p = fmaf(p, w, 0.00943887047f);
        p = fmaf(p, w, 1.00167406f);
        p = fmaf(p, w, 2.83297682f);
    }
    return p * x;
}

#define TF_ROUND(x0, x1, R) { x0 += x1; x1 = (x1 << (R)) | (x1 >> (32 - (R))); x1 ^= x0; }

__device__ __forceinline__ void threefry_(unsigned c0, unsigned c1, unsigned& r0, unsigned& r1) {
    const unsigned ks0 = 0u, ks1 = 42u, ks2 = 0x1BD11BDAu ^ 0u ^ 42u;
    unsigned x0 = c0 + ks0, x1 = c1 + ks1;
    TF_ROUND(x0,x1,13) TF_ROUND(x0,x1,15) TF_ROUND(x0,x1,26) TF_ROUND(x0,x1,6)
    x0 += ks1; x1 += ks2 + 1u;
    TF_ROUND(x0,x1,17) TF_ROUND(x0,x1,29) TF_ROUND(x0,x1,16) TF_ROUND(x0,x1,24)
    x0 += ks2; x1 += ks0 + 2u;
    TF_ROUND(x0,x1,13) TF_ROUND(x0,x1,15) TF_ROUND(x0,x1,26) TF_ROUND(x0,x1,6)
    x0 += ks0; x1 += ks1 + 3u;
    TF_ROUND(x0,x1,17) TF_ROUND(x0,x1,29) TF_ROUND(x0,x1,16) TF_ROUND(x0,x1,24)
    x0 += ks1; x1 += ks2 + 4u;
    TF_ROUND(x0,x1,13) TF_ROUND(x0,x1,15) TF_ROUND(x0,x1,26) TF_ROUND(x0,x1,6)
    x0 += ks2; x1 += ks0 + 5u;
    r0 = x0; r1 = x1;
}

// eps[i]: bits = o0 ^ o1 of threefry2x32(key(0,42), (0, i))  [verified round 5]
__device__ __forceinline__ float jax_normal_(unsigned i) {
    unsigned o0, o1;
    threefry_(0u, i, o0, o1);
    unsigned bits = o0 ^ o1;
    unsigned fb = (bits >> 9) | 0x3F800000u;
    float f = __uint_as_float(fb) - 1.0f;
    const float lo = -0.99999994f;
    float u = f * 2.0f + lo;
    u = fmaxf(lo, u);
    return 1.41421356237f * erfinvf_(u);
}

// fp32 -> bf16 RNE
__device__ __forceinline__ ushort_t f2bf(float f) {
    unsigned u = __float_as_uint(f);
    return (ushort_t)((u + 0x7FFFu + ((u >> 16) & 1u)) >> 16);
}

// swizzled bf16 mirror index (ushort units): row stride 256, 16B-chunk XOR swizzle
__device__ __forceinline__ int midx(int row, int k) {
    int chunk = k >> 3;
    return row * 256 + (((chunk ^ (row & 7)) << 3) | (k & 7));
}

// bf16 weight fragment load (WBF=1: from bf16 blob; else convert fp32 inline)
template<int WBF>
__device__ __forceinline__ short8 ldw(const ushort_t* __restrict__ Wbf,
                                      const float* __restrict__ Wf,
                                      int row, int k0) {
    if (WBF) {
        return *(const short8*)(Wbf + (size_t)row * 256 + k0);
    } else {
        const float4 w0 = *(const float4*)(Wf + (size_t)row * 256 + k0);
        const float4 w1 = *(const float4*)(Wf + (size_t)row * 256 + k0 + 4);
        union { ushort_t u[8]; short8 v; } bb;
        bb.u[0] = f2bf(w0.x); bb.u[1] = f2bf(w0.y); bb.u[2] = f2bf(w0.z); bb.u[3] = f2bf(w0.w);
        bb.u[4] = f2bf(w1.x); bb.u[5] = f2bf(w1.y); bb.u[6] = f2bf(w1.z); bb.u[7] = f2bf(w1.w);
        return bb.v;
    }
}

typedef const float (*cmat)[HD];

// ---------------- fp32 quad-coop k-quarter qmm (encoder only; verified R12) ----------------
__device__ __forceinline__ void qmm(const float4* __restrict__ W4, cmat in,
                                    float& r0, float& r1,
                                    const int oj, const int s, const int kh, const int t8,
                                    float (*__restrict__ part)[4][RB][256], const int pb)
{
    float a0[RB], a1[RB], a2[RB], a3[RB];
#pragma unroll
    for (int r = 0; r < RB; ++r) { a0[r] = 0.f; a1[r] = 0.f; a2[r] = 0.f; a3[r] = 0.f; }
    const float4* wp = W4 + (size_t)oj * 64 + kh * 16 + s;
#pragma unroll 2
    for (int g = 0; g < 4; ++g) {
        const float4 w0 = wp[g * 4];
        const float4 w1 = wp[g * 4 + 4096];
        const float4 w2 = wp[g * 4 + 8192];
        const float4 w3 = wp[g * 4 + 12288];
        const int ko = kh * 64 + g * 16 + s * 4;
#pragma unroll
        for (int r = 0; r < RB; ++r) {
            const float4 av = *(const float4*)(&in[r][ko]);
            a0[r] = fmaf(av.w, w0.w, fmaf(av.z, w0.z, fmaf(av.y, w0.y, fmaf(av.x, w0.x, a0[r]))));
            a1[r] = fmaf(av.w, w1.w, fmaf(av.z, w1.z, fmaf(av.y, w1.y, fmaf(av.x, w1.x, a1[r]))));
            a2[r] = fmaf(av.w, w2.w, fmaf(av.z, w2.z, fmaf(av.y, w2.y, fmaf(av.x, w2.x, a2[r]))));
            a3[r] = fmaf(av.w, w3.w, fmaf(av.z, w3.z, fmaf(av.y, w3.y, fmaf(av.x, w3.x, a3[r]))));
        }
    }
    float mine[RB];
#pragma unroll
    for (int r = 0; r < RB; ++r) {
        float v0 = a0[r]; v0 += __shfl_xor(v0, 1); v0 += __shfl_xor(v0, 2);
        float v1 = a1[r]; v1 += __shfl_xor(v1, 1); v1 += __shfl_xor(v1, 2);
        float v2 = a2[r]; v2 += __shfl_xor(v2, 1); v2 += __shfl_xor(v2, 2);
        float v3 = a3[r]; v3 += __shfl_xor(v3, 1); v3 += __shfl_xor(v3, 2);
        mine[r] = (s == 0) ? v0 : (s == 1) ? v1 : (s == 2) ? v2 : v3;
    }
    const int R0 = kh * 2, R1 = R0 + 1;
#pragma unroll
    for (int r = 0; r < RB; ++r) {
        if (r != R0 && r != R1) part[pb][kh][r][t8] = mine[r];
    }
    __syncthreads();
    float s0 = mine[R0], s1 = mine[R1];
#pragma unroll
    for (int q = 1; q < 4; ++q) {
        const int qq = (kh + q) & 3;
        s0 += part[pb][qq][R0][t8];
        s1 += part[pb][qq][R1][t8];
    }
    r0 = s0; r1 = s1;
}

// MFMA over K=256 with preloaded B fragments
__device__ __forceinline__ f32x4 mfma8(const ushort_t* __restrict__ inbf,
                                       const short8 (&B)[8], const int lm, const int kb) {
    f32x4 acc = {0.f, 0.f, 0.f, 0.f};
#pragma unroll
    for (int kt = 0; kt < 8; ++kt) {
        short8 a = *(const short8*)(inbf + midx(lm, kt * 32 + kb * 8));
        acc = __builtin_amdgcn_mfma_f32_16x16x32_bf16(a, B[kt], acc, 0, 0, 0);
    }
    return acc;
}

template<int WBF>
__device__ __forceinline__ void loadB(short8 (&B)[8], const ushort_t* __restrict__ Wbf,
                                      const float* __restrict__ Wf, const int jo, const int kb) {
#pragma unroll
    for (int kt = 0; kt < 8; ++kt)
        B[kt] = ldw<WBF>(Wbf, Wf, jo, kt * 32 + kb * 8);
}

// ---------------- weight bf16 conversion prepass ----------------
// layout: [0,64K) O1 | [64K,128K) O2 | [128K,192K) O3 | [192K,256K) O4 | [256K,448K) Whh
__global__ void cvt_k(const float* __restrict__ o1, const float* __restrict__ o2,
                      const float* __restrict__ o3, const float* __restrict__ o4,
                      const float* __restrict__ whh, ushort_t* __restrict__ out) {
    int i = blockIdx.x * blockDim.x + threadIdx.x;
    if (i < 262144) {
        int m = i >> 16, r = i & 65535;
        const float* s = (m == 0) ? o1 : (m == 1) ? o2 : (m == 2) ? o3 : o4;
        out[i] = f2bf(s[r]);
    } else if (i < 458752) {
        out[i] = f2bf(whh[i - 262144]);
    }
}

// ---------------- fused pipeline kernel ----------------
template<int WBF>
__global__ __launch_bounds__(TB) void fused_kernel(
    const float* __restrict__ x,
    const float* __restrict__ meta,
    const float* __restrict__ W_ih,
    const float* __restrict__ W_hh,
    const float* __restrict__ b_ih,
    const float* __restrict__ b_hh,
    const float* __restrict__ eW1,
    const float* __restrict__ eb1,
    const float* __restrict__ eW2,
    const float* __restrict__ eb2,
    const float* __restrict__ oW1, const float* __restrict__ ob1,
    const float* __restrict__ oW2, const float* __restrict__ ob2,
    const float* __restrict__ oW3, const float* __restrict__ ob3,
    const float* __restrict__ oW4, const float* __restrict__ ob4,
    const float* __restrict__ outW,
    const float* __restrict__ outb,
    const ushort_t* __restrict__ wsbf,
    float* __restrict__ out)
{
    const int tid = threadIdx.x;
    // encoder fp32-qmm mapping
    const int kh  = tid >> 8;
    const int t8  = tid & 255;
    const int oj  = t8 >> 2;
    const int sq  = t8 & 3;
    const int jj  = oj + 64 * sq;
    const int R0q = kh * 2, R1q = R0q + 1;
    // MFMA mapping
    const int l   = tid & 63;
    const int w   = tid >> 6;            // wave / n-tile base
    const int lm  = l & 15;              // A batch-row / B out-col within tile
    const int kb  = l >> 4;              // k-slice
    const int jo  = w * 16 + lm;         // owned output col (0..255)
    const int er2 = (l >> 4) & 1;        // epilogue row group (safe for all lanes)
    const bool act = (l < 32);
    const int b0  = blockIdx.x * RB;

    __shared__ float h0[RB][HD];                    // fp32 h / y master
    __shared__ float tA[RB][HD];
    __shared__ float xall[RB][TT * 4];
    __shared__ float part[2][4][RB][256];           // 64 KB (encoder)
    __shared__ float red[TB];
    __shared__ __align__(16) ushort_t mir[4][16][256];  // 32 KB bf16 mirrors
    __shared__ float meta_s[RB][4];
    __shared__ float dt_s[RB];

    const float4* E1f4 = (const float4*)eW1;
    const float4* E2f4 = (const float4*)eW2;
    ushort_t* YBF = &mir[0][0][0];
    ushort_t* YTB = &mir[1][0][0];
    ushort_t* T1B = &mir[2][0][0];
    ushort_t* T2B = &mir[3][0][0];
    const ushort_t* wsO1 = wsbf;
    const ushort_t* wsO2 = wsbf + 65536;
    const ushort_t* wsO3 = wsbf + 131072;
    const ushort_t* wsO4 = wsbf + 196608;
    const ushort_t* wsWhh = wsbf + 262144;

    cmat tAc = (cmat)tA;

    int pb = 0;
    auto QMM = [&](const float4* W4p, cmat inp, float& q0, float& q1) {
        qmm(W4p, inp, q0, q1, oj, sq, kh, t8, part, pb);
        pb ^= 1;
    };

    // ---- stage x, meta; zero h0 and mirrors ----
#pragma unroll
    for (int i = 0; i < 2; ++i) {
        int idx = tid + i * TB;
        int r = idx >> 8, c = idx & 255;
        xall[r][c] = x[(size_t)(b0 + r) * 256 + c];
    }
    if (tid < RB * 4) { int r = tid >> 2, mm = tid & 3; meta_s[r][mm] = meta[(b0 + r) * 4 + mm]; }
    if (tid < 2 * HD) { int r = tid >> 8, c = tid & 255;
        h0[r][c] = 0.0f; h0[r + 2][c] = 0.0f; h0[r + 4][c] = 0.0f; h0[r + 6][c] = 0.0f; }
    {
        unsigned* mz = (unsigned*)&mir[0][0][0];   // 8192 u32 = 32 KB
#pragma unroll
        for (int i = 0; i < 8; ++i) mz[tid + i * TB] = 0u;
    }
    __syncthreads();
    if (tid < RB) dt_s[tid] = (xall[tid][TT * 4 - 4] - xall[tid][0]) * (1.0f / (float)NST);

    // ---- GRU per-lane x-side constants for owned col jo ----
    float wxr[4], wxz[4], wxn[4];
#pragma unroll
    for (int d = 0; d < 4; ++d) {
        wxr[d] = W_ih[(size_t)jo * 8 + d];
        wxz[d] = W_ih[(size_t)(jo + 256) * 8 + d];
        wxn[d] = W_ih[(size_t)(jo + 512) * 8 + d];
    }
    float base_r[4], base_z[4], base_xn[4];
    {
        float mwr[4], mwz[4], mwn[4];
#pragma unroll
        for (int mm = 0; mm < 4; ++mm) {
            mwr[mm] = W_ih[(size_t)jo * 8 + 4 + mm];
            mwz[mm] = W_ih[(size_t)(jo + 256) * 8 + 4 + mm];
            mwn[mm] = W_ih[(size_t)(jo + 512) * 8 + 4 + mm];
        }
        const float bir = b_ih[jo], biz = b_ih[jo + 256], bin_ = b_ih[jo + 512];
        const float bhr = b_hh[jo], bhz = b_hh[jo + 256];
#pragma unroll
        for (int r = 0; r < 4; ++r) {
            const int R = er2 * 4 + r;                 // rows 0..7 (for act lanes)
            float sr = bir + bhr, sz = biz + bhz, sn = bin_;
#pragma unroll
            for (int mm = 0; mm < 4; ++mm) {
                float mv = meta_s[R][mm];
                sr = fmaf(mv, mwr[mm], sr);
                sz = fmaf(mv, mwz[mm], sz);
                sn = fmaf(mv, mwn[mm], sn);
            }
            base_r[r] = sr; base_z[r] = sz; base_xn[r] = sn;
        }
    }
    const float bhn = b_hh[512 + jo];

    // ---- GRU: 64 steps, MFMA bf16, mirror ping-pong, ONE barrier/step ----
    int p = 0;
#pragma unroll 1
    for (int t = 0; t < TT; ++t) {
        const ushort_t* YHp = &mir[p][0][0];
        f32x4 aR = {0.f,0.f,0.f,0.f}, aZ = {0.f,0.f,0.f,0.f}, aN = {0.f,0.f,0.f,0.f};
#pragma unroll 2
        for (int kt = 0; kt < 8; ++kt) {
            const int k0 = kt * 32 + kb * 8;
            short8 a  = *(const short8*)(YHp + midx(lm, k0));
            short8 br = ldw<WBF>(wsWhh, W_hh, jo, k0);
            short8 bz = ldw<WBF>(wsWhh, W_hh, jo + 256, k0);
            short8 bn = ldw<WBF>(wsWhh, W_hh, jo + 512, k0);
            aR = __builtin_amdgcn_mfma_f32_16x16x32_bf16(a, br, aR, 0, 0, 0);
            aZ = __builtin_amdgcn_mfma_f32_16x16x32_bf16(a, bz, aZ, 0, 0, 0);
            aN = __builtin_amdgcn_mfma_f32_16x16x32_bf16(a, bn, aN, 0, 0, 0);
        }
        if (act) {
            ushort_t* YHn = &mir[p ^ 1][0][0];
#pragma unroll
            for (int r = 0; r < 4; ++r) {
                const int R = er2 * 4 + r;
                float xr = base_r[r], xz = base_z[r], xn = base_xn[r];
#pragma unroll
                for (int d = 0; d < 4; ++d) {
                    float xv = xall[R][t * 4 + d];
                    xr = fmaf(xv, wxr[d], xr);
                    xz = fmaf(xv, wxz[d], xz);
                    xn = fmaf(xv, wxn[d], xn);
                }
                float rg = sigmoidf_(xr + aR[r]);
                float zg = sigmoidf_(xz + aZ[r]);
                float ng = tanhf_(fmaf(rg, aN[r] + bhn, xn));
                float hp = h0[R][jo];
                float hnew = fmaf(zg, hp - ng, ng);
                h0[R][jo] = hnew;                     // fp32 master (single owner)
                YHn[midx(R, jo)] = f2bf(hnew);        // bf16 mirror for next step
            }
        }
        __syncthreads();
        p ^= 1;
    }

    // ---- encoder + sample y0 (fp32, exact) ----
    {
        float a0, a1;
        QMM(E1f4, (cmat)h0, a0, a1);
        const float eb1j = eb1[jj];
        tA[R0q][jj] = fmaxf(a0 + eb1j, 0.0f);
        tA[R1q][jj] = fmaxf(a1 + eb1j, 0.0f);
        __syncthreads();

        float aM0, aM1, aS0, aS1;
        QMM(E2f4,            tAc, aM0, aM1);
        QMM(E2f4 + 256 * 64, tAc, aS0, aS1);
        const float bm = eb2[jj], bs = eb2[256 + jj];
        float e0 = jax_normal_((unsigned)((b0 + R0q) * HD + jj));
        float e1 = jax_normal_((unsigned)((b0 + R1q) * HD + jj));
        float y0a = fmaf(e0, aS0 + bs, aM0 + bm);
        float y0b = fmaf(e1, aS1 + bs, aM1 + bm);
        h0[R0q][jj] = y0a;
        h0[R1q][jj] = y0b;
        YBF[midx(R0q, jj)] = f2bf(y0a);
        YBF[midx(R1q, jj)] = f2bf(y0b);
        __syncthreads();
    }

    // ---- dopri5: MFMA bf16 ODE with cross-barrier B prefetch ----
    const float A21 = (float)(1.0/5.0);
    const float A31 = (float)(3.0/40.0),      A32 = (float)(9.0/40.0);
    const float A41 = (float)(44.0/45.0),     A42 = (float)(-56.0/15.0),    A43 = (float)(32.0/9.0);
    const float A51 = (float)(19372.0/6561.0),A52 = (float)(-25360.0/2187.0),
                A53 = (float)(64448.0/6561.0),A54 = (float)(-212.0/729.0);
    const float A61 = (float)(9017.0/3168.0), A62 = (float)(-355.0/33.0),
                A63 = (float)(46732.0/5247.0),A64 = (float)(49.0/176.0),    A65 = (float)(-5103.0/18656.0);
    const float B1f = (float)(35.0/384.0),    B3f = (float)(500.0/1113.0),  B4f = (float)(125.0/192.0),
                B5f = (float)(-2187.0/6784.0),B6f = (float)(11.0/84.0);

    const float o1b = ob1[jo], o2b = ob2[jo], o3b = ob3[jo], o4b = ob4[jo];
    float dtv[4];
    if (act) {
#pragma unroll
        for (int r = 0; r < 4; ++r) dtv[r] = dt_s[er2 * 4 + r];
    }
    float k1[4], k2[4], k3[4], k4[4], k5[4], k6[4];

    short8 BA[8], BB[8];
    loadB<WBF>(BA, wsO1, oW1, jo, kb);    // prologue: L1 weights

#pragma unroll 1
    for (int st = 0; st < NST; ++st) {
#pragma unroll 1
        for (int stage = 0; stage < 6; ++stage) {
            const ushort_t* in0 = (stage == 0) ? YBF : YTB;
            // L1 (BA ready); prefetch L2
            loadB<WBF>(BB, wsO2, oW2, jo, kb);
            f32x4 acc = mfma8(in0, BA, lm, kb);
            if (act) {
#pragma unroll
                for (int r = 0; r < 4; ++r)
                    T1B[midx(er2 * 4 + r, jo)] = f2bf(seluf_(acc[r] + o1b));
            }
            __syncthreads();
            // L2 (BB); prefetch L3
            loadB<WBF>(BA, wsO3, oW3, jo, kb);
            acc = mfma8(T1B, BB, lm, kb);
            if (act) {
#pragma unroll
                for (int r = 0; r < 4; ++r)
                    T2B[midx(er2 * 4 + r, jo)] = f2bf(seluf_(acc[r] + o2b));
            }
            __syncthreads();
            // L3 (BA); prefetch L4
            loadB<WBF>(BB, wsO4, oW4, jo, kb);
            acc = mfma8(T2B, BA, lm, kb);
            if (act) {
#pragma unroll
                for (int r = 0; r < 4; ++r)
                    T1B[midx(er2 * 4 + r, jo)] = f2bf(seluf_(acc[r] + o3b));
            }
            __syncthreads();
            // L4 (BB); prefetch next L1
            loadB<WBF>(BA, wsO1, oW1, jo, kb);
            acc = mfma8(T1B, BB, lm, kb);
            if (act) {
#pragma unroll
                for (int r = 0; r < 4; ++r) {
                    const int row = er2 * 4 + r;
                    const float kc = acc[r] + o4b;
                    const float yv = h0[row][jo];
                    float sm;
                    switch (stage) {
                    case 0: k1[r] = kc; sm = A21 * kc; break;
                    case 1: k2[r] = kc; sm = fmaf(A32, kc, A31 * k1[r]); break;
                    case 2: k3[r] = kc; sm = fmaf(A43, kc, fmaf(A42, k2[r], A41 * k1[r])); break;
                    case 3: k4[r] = kc; sm = fmaf(A54, kc, fmaf(A53, k3[r], fmaf(A52, k2[r], A51 * k1[r]))); break;
                    case 4: k5[r] = kc; sm = fmaf(A65, kc, fmaf(A64, k4[r],
                                     fmaf(A63, k3[r], fmaf(A62, k2[r], A61 * k1[r])))); break;
                    default: k6[r] = kc; sm = fmaf(B6f, kc, fmaf(B5f, k5[r],
                                      fmaf(B4f, k4[r], fmaf(B3f, k3[r], B1f * k1[r])))); break;
                    }
                    const float yn = fmaf(dtv[r], sm, yv);
                    if (stage < 5) {
                        YTB[midx(row, jo)] = f2bf(yn);
                    } else {
                        h0[row][jo] = yn;
                        YBF[midx(row, jo)] = f2bf(yn);
                    }
                }
            }
            __syncthreads();
        }
    }

    // ---- output head ----
#pragma unroll 1
    for (int rp4 = 0; rp4 < 2; ++rp4) {
        const int R = rp4 * 4 + (tid >> 8);
        red[tid] = h0[R][t8] * outW[t8];
        __syncthreads();
        for (int sw = 128; sw > 0; sw >>= 1) {
            if (t8 < sw) red[tid] += red[tid + sw];
            __syncthreads();
        }
        if (t8 == 0) {
            float acc = red[tid] + outb[0];
#pragma unroll
            for (int mm = 0; mm < 4; ++mm) acc = fmaf(meta_s[R][mm], outW[HD + mm], acc);
            out[b0 + R] = acc;
        }
        __syncthreads();
    }
}

extern "C" void kernel_launch(void* const* d_in, const int* in_sizes, int n_in,
                              void* d_out, int out_size, void* d_ws, size_t ws_size,
                              hipStream_t stream) {
    const float* x    = (const float*)d_in[0];
    const float* meta = (const float*)d_in[1];
    const float* W_ih = (const float*)d_in[2];
    const float* W_hh = (const float*)d_in[3];
    const float* b_ih = (const float*)d_in[4];
    const float* b_hh = (const float*)d_in[5];
    const float* eW1  = (const float*)d_in[6];
    const float* eb1  = (const float*)d_in[7];
    const float* eW2  = (const float*)d_in[8];
    const float* eb2  = (const float*)d_in[9];
    const float* oW1  = (const float*)d_in[10];
    const float* ob1  = (const float*)d_in[11];
    const float* oW2  = (const float*)d_in[12];
    const float* ob2  = (const float*)d_in[13];
    const float* oW3  = (const float*)d_in[14];
    const float* ob3  = (const float*)d_in[15];
    const float* oW4  = (const float*)d_in[16];
    const float* ob4  = (const float*)d_in[17];
    const float* outW = (const float*)d_in[18];
    const float* outb = (const float*)d_in[19];

    const size_t need = (size_t)458752 * sizeof(ushort_t);   // 896 KB
    const bool wbf = (d_ws != nullptr) && (ws_size >= need);

    if (wbf) {
        cvt_k<<<1792, 256, 0, stream>>>(oW1, oW2, oW3, oW4, W_hh, (ushort_t*)d_ws);
        fused_kernel<1><<<BSZ / RB, TB, 0, stream>>>(x, meta, W_ih, W_hh, b_ih, b_hh,
                                                     eW1, eb1, eW2, eb2,
                                                     oW1, ob1, oW2, ob2, oW3, ob3, oW4, ob4,
                                                     outW, outb, (const ushort_t*)d_ws,
                                                     (float*)d_out);
    } else {
        fused_kernel<0><<<BSZ / RB, TB, 0, stream>>>(x, meta, W_ih, W_hh, b_ih, b_hh,
                                                     eW1, eb1, eW2, eb2,
                                                     oW1, ob1, oW2, ob2, oW3, ob3, oW4, ob4,
                                                     outW, outb, (const ushort_t*)nullptr,
                                                     (float*)d_out);
    }
}

// Round 15
// 2723.546 us; speedup vs baseline: 2.8652x; 1.0011x over previous
//
#include <hip/hip_runtime.h>
#include <math.h>

#define HD   256
#define RB   8      // batch rows per block -> grid 256 = 1 block/CU
#define TB   1024   // 16 waves, 4/SIMD
#define TT   64
#define NST  32
#define BSZ  2048

typedef __attribute__((ext_vector_type(8))) short short8;
typedef __attribute__((ext_vector_type(4))) float f32x4;
typedef unsigned short ushort_t;

// ---------------- math helpers ----------------
__device__ __forceinline__ float sigmoidf_(float x) {
    return 1.0f / (1.0f + __expf(-x));
}
__device__ __forceinline__ float tanhf_(float x) {
    float e = __expf(2.0f * x);
    return 1.0f - 2.0f / (e + 1.0f);
}
__device__ __forceinline__ float seluf_(float x) {
    const float a = 1.6732632423543772f, s = 1.0507009873554805f;
    return x > 0.0f ? s * x : s * a * (__expf(x) - 1.0f);
}
__device__ __forceinline__ float erfinvf_(float x) {
    float w = -log1pf(-x * x);
    float p;
    if (w < 5.0f) {
        w -= 2.5f;
        p = 2.81022636e-08f;
        p = fmaf(p, w, 3.43273939e-07f);
        p = fmaf(p, w, -3.5233877e-06f);
        p = fmaf(p, w, -4.39150654e-06f);
        p = fmaf(p, w, 0.00021858087f);
        p = fmaf(p, w, -0.00125372503f);
        p = fmaf(p, w, -0.00417768164f);
        p = fmaf(p, w, 0.246640727f);
        p = fmaf(p, w, 1.50140941f);
    } else {
        w = sqrtf(w) - 3.0f;
        p = -0.000200214257f;
        p = fmaf(p, w, 0.000100950558f);
        p = fmaf(p, w, 0.00134934322f);
        p = fmaf(p, w, -0.00367342844f);
        p = fmaf(p, w, 0.00573950773f);
        p = fmaf(p, w, -0.0076224613f);
        p = fmaf(p, w, 0.00943887047f);
        p = fmaf(p, w, 1.00167406f);
        p = fmaf(p, w, 2.83297682f);
    }
    return p * x;
}

#define TF_ROUND(x0, x1, R) { x0 += x1; x1 = (x1 << (R)) | (x1 >> (32 - (R))); x1 ^= x0; }

__device__ __forceinline__ void threefry_(unsigned c0, unsigned c1, unsigned& r0, unsigned& r1) {
    const unsigned ks0 = 0u, ks1 = 42u, ks2 = 0x1BD11BDAu ^ 0u ^ 42u;
    unsigned x0 = c0 + ks0, x1 = c1 + ks1;
    TF_ROUND(x0,x1,13) TF_ROUND(x0,x1,15) TF_ROUND(x0,x1,26) TF_ROUND(x0,x1,6)
    x0 += ks1; x1 += ks2 + 1u;
    TF_ROUND(x0,x1,17) TF_ROUND(x0,x1,29) TF_ROUND(x0,x1,16) TF_ROUND(x0,x1,24)
    x0 += ks2; x1 += ks0 + 2u;
    TF_ROUND(x0,x1,13) TF_ROUND(x0,x1,15) TF_ROUND(x0,x1,26) TF_ROUND(x0,x1,6)
    x0 += ks0; x1 += ks1 + 3u;
    TF_ROUND(x0,x1,17) TF_ROUND(x0,x1,29) TF_ROUND(x0,x1,16) TF_ROUND(x0,x1,24)
    x0 += ks1; x1 += ks2 + 4u;
    TF_ROUND(x0,x1,13) TF_ROUND(x0,x1,15) TF_ROUND(x0,x1,26) TF_ROUND(x0,x1,6)
    x0 += ks2; x1 += ks0 + 5u;
    r0 = x0; r1 = x1;
}

// eps[i]: bits = o0 ^ o1 of threefry2x32(key(0,42), (0, i))  [verified round 5]
__device__ __forceinline__ float jax_normal_(unsigned i) {
    unsigned o0, o1;
    threefry_(0u, i, o0, o1);
    unsigned bits = o0 ^ o1;
    unsigned fb = (bits >> 9) | 0x3F800000u;
    float f = __uint_as_float(fb) - 1.0f;
    const float lo = -0.99999994f;
    float u = f * 2.0f + lo;
    u = fmaxf(lo, u);
    return 1.41421356237f * erfinvf_(u);
}

// fp32 -> bf16 RNE
__device__ __forceinline__ ushort_t f2bf(float f) {
    unsigned u = __float_as_uint(f);
    return (ushort_t)((u + 0x7FFFu + ((u >> 16) & 1u)) >> 16);
}

// swizzled bf16 mirror index (ushort units): row stride 256, 16B-chunk XOR swizzle
__device__ __forceinline__ int midx(int row, int k) {
    int chunk = k >> 3;
    return row * 256 + (((chunk ^ (row & 7)) << 3) | (k & 7));
}

// bf16 weight fragment load (WBF=1: from bf16 blob; else convert fp32 inline)
template<int WBF>
__device__ __forceinline__ short8 ldw(const ushort_t* __restrict__ Wbf,
                                      const float* __restrict__ Wf,
                                      int row, int k0) {
    if (WBF) {
        return *(const short8*)(Wbf + (size_t)row * 256 + k0);
    } else {
        const float4 w0 = *(const float4*)(Wf + (size_t)row * 256 + k0);
        const float4 w1 = *(const float4*)(Wf + (size_t)row * 256 + k0 + 4);
        union { ushort_t u[8]; short8 v; } bb;
        bb.u[0] = f2bf(w0.x); bb.u[1] = f2bf(w0.y); bb.u[2] = f2bf(w0.z); bb.u[3] = f2bf(w0.w);
        bb.u[4] = f2bf(w1.x); bb.u[5] = f2bf(w1.y); bb.u[6] = f2bf(w1.z); bb.u[7] = f2bf(w1.w);
        return bb.v;
    }
}

typedef const float (*cmat)[HD];

// ---------------- fp32 quad-coop k-quarter qmm (encoder only; verified R12) ----------------
__device__ __forceinline__ void qmm(const float4* __restrict__ W4, cmat in,
                                    float& r0, float& r1,
                                    const int oj, const int s, const int kh, const int t8,
                                    float (*__restrict__ part)[4][RB][256], const int pb)
{
    float a0[RB], a1[RB], a2[RB], a3[RB];
#pragma unroll
    for (int r = 0; r < RB; ++r) { a0[r] = 0.f; a1[r] = 0.f; a2[r] = 0.f; a3[r] = 0.f; }
    const float4* wp = W4 + (size_t)oj * 64 + kh * 16 + s;
#pragma unroll 2
    for (int g = 0; g < 4; ++g) {
        const float4 w0 = wp[g * 4];
        const float4 w1 = wp[g * 4 + 4096];
        const float4 w2 = wp[g * 4 + 8192];
        const float4 w3 = wp[g * 4 + 12288];
        const int ko = kh * 64 + g * 16 + s * 4;
#pragma unroll
        for (int r = 0; r < RB; ++r) {
            const float4 av = *(const float4*)(&in[r][ko]);
            a0[r] = fmaf(av.w, w0.w, fmaf(av.z, w0.z, fmaf(av.y, w0.y, fmaf(av.x, w0.x, a0[r]))));
            a1[r] = fmaf(av.w, w1.w, fmaf(av.z, w1.z, fmaf(av.y, w1.y, fmaf(av.x, w1.x, a1[r]))));
            a2[r] = fmaf(av.w, w2.w, fmaf(av.z, w2.z, fmaf(av.y, w2.y, fmaf(av.x, w2.x, a2[r]))));
            a3[r] = fmaf(av.w, w3.w, fmaf(av.z, w3.z, fmaf(av.y, w3.y, fmaf(av.x, w3.x, a3[r]))));
        }
    }
    float mine[RB];
#pragma unroll
    for (int r = 0; r < RB; ++r) {
        float v0 = a0[r]; v0 += __shfl_xor(v0, 1); v0 += __shfl_xor(v0, 2);
        float v1 = a1[r]; v1 += __shfl_xor(v1, 1); v1 += __shfl_xor(v1, 2);
        float v2 = a2[r]; v2 += __shfl_xor(v2, 1); v2 += __shfl_xor(v2, 2);
        float v3 = a3[r]; v3 += __shfl_xor(v3, 1); v3 += __shfl_xor(v3, 2);
        mine[r] = (s == 0) ? v0 : (s == 1) ? v1 : (s == 2) ? v2 : v3;
    }
    const int R0 = kh * 2, R1 = R0 + 1;
#pragma unroll
    for (int r = 0; r < RB; ++r) {
        if (r != R0 && r != R1) part[pb][kh][r][t8] = mine[r];
    }
    __syncthreads();
    float s0 = mine[R0], s1 = mine[R1];
#pragma unroll
    for (int q = 1; q < 4; ++q) {
        const int qq = (kh + q) & 3;
        s0 += part[pb][qq][R0][t8];
        s1 += part[pb][qq][R1][t8];
    }
    r0 = s0; r1 = s1;
}

// MFMA over K=256 with preloaded B fragments
__device__ __forceinline__ f32x4 mfma8(const ushort_t* __restrict__ inbf,
                                       const short8 (&B)[8], const int lm, const int kb) {
    f32x4 acc = {0.f, 0.f, 0.f, 0.f};
#pragma unroll
    for (int kt = 0; kt < 8; ++kt) {
        short8 a = *(const short8*)(inbf + midx(lm, kt * 32 + kb * 8));
        acc = __builtin_amdgcn_mfma_f32_16x16x32_bf16(a, B[kt], acc, 0, 0, 0);
    }
    return acc;
}

template<int WBF>
__device__ __forceinline__ void loadB(short8 (&B)[8], const ushort_t* __restrict__ Wbf,
                                      const float* __restrict__ Wf, const int jo, const int kb) {
#pragma unroll
    for (int kt = 0; kt < 8; ++kt)
        B[kt] = ldw<WBF>(Wbf, Wf, jo, kt * 32 + kb * 8);
}

// ---------------- weight bf16 conversion prepass ----------------
// layout: [0,64K) O1 | [64K,128K) O2 | [128K,192K) O3 | [192K,256K) O4 | [256K,448K) Whh
__global__ void cvt_k(const float* __restrict__ o1, const float* __restrict__ o2,
                      const float* __restrict__ o3, const float* __restrict__ o4,
                      const float* __restrict__ whh, ushort_t* __restrict__ out) {
    int i = blockIdx.x * blockDim.x + threadIdx.x;
    if (i < 262144) {
        int m = i >> 16, r = i & 65535;
        const float* s = (m == 0) ? o1 : (m == 1) ? o2 : (m == 2) ? o3 : o4;
        out[i] = f2bf(s[r]);
    } else if (i < 458752) {
        out[i] = f2bf(whh[i - 262144]);
    }
}

// ---------------- fused pipeline kernel ----------------
// __launch_bounds__(TB, 4): 4 waves/SIMD min -> 128-VGPR cap. LDS (~127KB) limits us
// to 1 block/CU anyway; without this the compiler targeted 8 waves/SIMD (64 VGPR)
// and spilled the BA/BB prefetch buffers to scratch (R14: 961 MB WRITE_SIZE).
template<int WBF>
__global__ __launch_bounds__(TB, 4) void fused_kernel(
    const float* __restrict__ x,
    const float* __restrict__ meta,
    const float* __restrict__ W_ih,
    const float* __restrict__ W_hh,
    const float* __restrict__ b_ih,
    const float* __restrict__ b_hh,
    const float* __restrict__ eW1,
    const float* __restrict__ eb1,
    const float* __restrict__ eW2,
    const float* __restrict__ eb2,
    const float* __restrict__ oW1, const float* __restrict__ ob1,
    const float* __restrict__ oW2, const float* __restrict__ ob2,
    const float* __restrict__ oW3, const float* __restrict__ ob3,
    const float* __restrict__ oW4, const float* __restrict__ ob4,
    const float* __restrict__ outW,
    const float* __restrict__ outb,
    const ushort_t* __restrict__ wsbf,
    float* __restrict__ out)
{
    const int tid = threadIdx.x;
    // encoder fp32-qmm mapping
    const int kh  = tid >> 8;
    const int t8  = tid & 255;
    const int oj  = t8 >> 2;
    const int sq  = t8 & 3;
    const int jj  = oj + 64 * sq;
    const int R0q = kh * 2, R1q = R0q + 1;
    // MFMA mapping
    const int l   = tid & 63;
    const int w   = tid >> 6;            // wave / n-tile base
    const int lm  = l & 15;              // A batch-row / B out-col within tile
    const int kb  = l >> 4;              // k-slice
    const int jo  = w * 16 + lm;         // owned output col (0..255)
    const int er2 = (l >> 4) & 1;        // epilogue row group (safe for all lanes)
    const bool act = (l < 32);
    const int b0  = blockIdx.x * RB;

    __shared__ float h0[RB][HD];                    // fp32 h / y master
    __shared__ float tA[RB][HD];
    __shared__ float xall[RB][TT * 4];
    __shared__ float part[2][4][RB][256];           // 64 KB (encoder)
    __shared__ float red[TB];
    __shared__ __align__(16) ushort_t mir[4][16][256];  // 32 KB bf16 mirrors
    __shared__ float meta_s[RB][4];
    __shared__ float dt_s[RB];

    const float4* E1f4 = (const float4*)eW1;
    const float4* E2f4 = (const float4*)eW2;
    ushort_t* YBF = &mir[0][0][0];
    ushort_t* YTB = &mir[1][0][0];
    ushort_t* T1B = &mir[2][0][0];
    ushort_t* T2B = &mir[3][0][0];
    const ushort_t* wsO1 = wsbf;
    const ushort_t* wsO2 = wsbf + 65536;
    const ushort_t* wsO3 = wsbf + 131072;
    const ushort_t* wsO4 = wsbf + 196608;
    const ushort_t* wsWhh = wsbf + 262144;

    cmat tAc = (cmat)tA;

    int pb = 0;
    auto QMM = [&](const float4* W4p, cmat inp, float& q0, float& q1) {
        qmm(W4p, inp, q0, q1, oj, sq, kh, t8, part, pb);
        pb ^= 1;
    };

    // ---- stage x, meta; zero h0 and mirrors ----
#pragma unroll
    for (int i = 0; i < 2; ++i) {
        int idx = tid + i * TB;
        int r = idx >> 8, c = idx & 255;
        xall[r][c] = x[(size_t)(b0 + r) * 256 + c];
    }
    if (tid < RB * 4) { int r = tid >> 2, mm = tid & 3; meta_s[r][mm] = meta[(b0 + r) * 4 + mm]; }
    if (tid < 2 * HD) { int r = tid >> 8, c = tid & 255;
        h0[r][c] = 0.0f; h0[r + 2][c] = 0.0f; h0[r + 4][c] = 0.0f; h0[r + 6][c] = 0.0f; }
    {
        unsigned* mz = (unsigned*)&mir[0][0][0];   // 8192 u32 = 32 KB
#pragma unroll
        for (int i = 0; i < 8; ++i) mz[tid + i * TB] = 0u;
    }
    __syncthreads();
    if (tid < RB) dt_s[tid] = (xall[tid][TT * 4 - 4] - xall[tid][0]) * (1.0f / (float)NST);

    // ---- GRU per-lane x-side constants for owned col jo ----
    float wxr[4], wxz[4], wxn[4];
#pragma unroll
    for (int d = 0; d < 4; ++d) {
        wxr[d] = W_ih[(size_t)jo * 8 + d];
        wxz[d] = W_ih[(size_t)(jo + 256) * 8 + d];
        wxn[d] = W_ih[(size_t)(jo + 512) * 8 + d];
    }
    float base_r[4], base_z[4], base_xn[4];
    {
        float mwr[4], mwz[4], mwn[4];
#pragma unroll
        for (int mm = 0; mm < 4; ++mm) {
            mwr[mm] = W_ih[(size_t)jo * 8 + 4 + mm];
            mwz[mm] = W_ih[(size_t)(jo + 256) * 8 + 4 + mm];
            mwn[mm] = W_ih[(size_t)(jo + 512) * 8 + 4 + mm];
        }
        const float bir = b_ih[jo], biz = b_ih[jo + 256], bin_ = b_ih[jo + 512];
        const float bhr = b_hh[jo], bhz = b_hh[jo + 256];
#pragma unroll
        for (int r = 0; r < 4; ++r) {
            const int R = er2 * 4 + r;                 // rows 0..7 (for act lanes)
            float sr = bir + bhr, sz = biz + bhz, sn = bin_;
#pragma unroll
            for (int mm = 0; mm < 4; ++mm) {
                float mv = meta_s[R][mm];
                sr = fmaf(mv, mwr[mm], sr);
                sz = fmaf(mv, mwz[mm], sz);
                sn = fmaf(mv, mwn[mm], sn);
            }
            base_r[r] = sr; base_z[r] = sz; base_xn[r] = sn;
        }
    }
    const float bhn = b_hh[512 + jo];

    // ---- GRU: 64 steps, MFMA bf16, mirror ping-pong, ONE barrier/step ----
    int p = 0;
#pragma unroll 1
    for (int t = 0; t < TT; ++t) {
        const ushort_t* YHp = &mir[p][0][0];
        f32x4 aR = {0.f,0.f,0.f,0.f}, aZ = {0.f,0.f,0.f,0.f}, aN = {0.f,0.f,0.f,0.f};
#pragma unroll 2
        for (int kt = 0; kt < 8; ++kt) {
            const int k0 = kt * 32 + kb * 8;
            short8 a  = *(const short8*)(YHp + midx(lm, k0));
            short8 br = ldw<WBF>(wsWhh, W_hh, jo, k0);
            short8 bz = ldw<WBF>(wsWhh, W_hh, jo + 256, k0);
            short8 bn = ldw<WBF>(wsWhh, W_hh, jo + 512, k0);
            aR = __builtin_amdgcn_mfma_f32_16x16x32_bf16(a, br, aR, 0, 0, 0);
            aZ = __builtin_amdgcn_mfma_f32_16x16x32_bf16(a, bz, aZ, 0, 0, 0);
            aN = __builtin_amdgcn_mfma_f32_16x16x32_bf16(a, bn, aN, 0, 0, 0);
        }
        if (act) {
            ushort_t* YHn = &mir[p ^ 1][0][0];
#pragma unroll
            for (int r = 0; r < 4; ++r) {
                const int R = er2 * 4 + r;
                float xr = base_r[r], xz = base_z[r], xn = base_xn[r];
#pragma unroll
                for (int d = 0; d < 4; ++d) {
                    float xv = xall[R][t * 4 + d];
                    xr = fmaf(xv, wxr[d], xr);
                    xz = fmaf(xv, wxz[d], xz);
                    xn = fmaf(xv, wxn[d], xn);
                }
                float rg = sigmoidf_(xr + aR[r]);
                float zg = sigmoidf_(xz + aZ[r]);
                float ng = tanhf_(fmaf(rg, aN[r] + bhn, xn));
                float hp = h0[R][jo];
                float hnew = fmaf(zg, hp - ng, ng);
                h0[R][jo] = hnew;                     // fp32 master (single owner)
                YHn[midx(R, jo)] = f2bf(hnew);        // bf16 mirror for next step
            }
        }
        __syncthreads();
        p ^= 1;
    }

    // ---- encoder + sample y0 (fp32, exact) ----
    {
        float a0, a1;
        QMM(E1f4, (cmat)h0, a0, a1);
        const float eb1j = eb1[jj];
        tA[R0q][jj] = fmaxf(a0 + eb1j, 0.0f);
        tA[R1q][jj] = fmaxf(a1 + eb1j, 0.0f);
        __syncthreads();

        float aM0, aM1, aS0, aS1;
        QMM(E2f4,            tAc, aM0, aM1);
        QMM(E2f4 + 256 * 64, tAc, aS0, aS1);
        const float bm = eb2[jj], bs = eb2[256 + jj];
        float e0 = jax_normal_((unsigned)((b0 + R0q) * HD + jj));
        float e1 = jax_normal_((unsigned)((b0 + R1q) * HD + jj));
        float y0a = fmaf(e0, aS0 + bs, aM0 + bm);
        float y0b = fmaf(e1, aS1 + bs, aM1 + bm);
        h0[R0q][jj] = y0a;
        h0[R1q][jj] = y0b;
        YBF[midx(R0q, jj)] = f2bf(y0a);
        YBF[midx(R1q, jj)] = f2bf(y0b);
        __syncthreads();
    }

    // ---- dopri5: MFMA bf16 ODE with cross-barrier B prefetch ----
    const float A21 = (float)(1.0/5.0);
    const float A31 = (float)(3.0/40.0),      A32 = (float)(9.0/40.0);
    const float A41 = (float)(44.0/45.0),     A42 = (float)(-56.0/15.0),    A43 = (float)(32.0/9.0);
    const float A51 = (float)(19372.0/6561.0),A52 = (float)(-25360.0/2187.0),
                A53 = (float)(64448.0/6561.0),A54 = (float)(-212.0/729.0);
    const float A61 = (float)(9017.0/3168.0), A62 = (float)(-355.0/33.0),
                A63 = (float)(46732.0/5247.0),A64 = (float)(49.0/176.0),    A65 = (float)(-5103.0/18656.0);
    const float B1f = (float)(35.0/384.0),    B3f = (float)(500.0/1113.0),  B4f = (float)(125.0/192.0),
                B5f = (float)(-2187.0/6784.0),B6f = (float)(11.0/84.0);

    const float o1b = ob1[jo], o2b = ob2[jo], o3b = ob3[jo], o4b = ob4[jo];
    float dtv[4];
    if (act) {
#pragma unroll
        for (int r = 0; r < 4; ++r) dtv[r] = dt_s[er2 * 4 + r];
    }
    float k1[4], k2[4], k3[4], k4[4], k5[4], k6[4];

    short8 BA[8], BB[8];
    loadB<WBF>(BA, wsO1, oW1, jo, kb);    // prologue: L1 weights

#pragma unroll 1
    for (int st = 0; st < NST; ++st) {
#pragma unroll 1
        for (int stage = 0; stage < 6; ++stage) {
            const ushort_t* in0 = (stage == 0) ? YBF : YTB;
            // L1 (BA ready); prefetch L2
            loadB<WBF>(BB, wsO2, oW2, jo, kb);
            f32x4 acc = mfma8(in0, BA, lm, kb);
            if (act) {
#pragma unroll
                for (int r = 0; r < 4; ++r)
                    T1B[midx(er2 * 4 + r, jo)] = f2bf(seluf_(acc[r] + o1b));
            }
            __syncthreads();
            // L2 (BB); prefetch L3
            loadB<WBF>(BA, wsO3, oW3, jo, kb);
            acc = mfma8(T1B, BB, lm, kb);
            if (act) {
#pragma unroll
                for (int r = 0; r < 4; ++r)
                    T2B[midx(er2 * 4 + r, jo)] = f2bf(seluf_(acc[r] + o2b));
            }
            __syncthreads();
            // L3 (BA); prefetch L4
            loadB<WBF>(BB, wsO4, oW4, jo, kb);
            acc = mfma8(T2B, BA, lm, kb);
            if (act) {
#pragma unroll
                for (int r = 0; r < 4; ++r)
                    T1B[midx(er2 * 4 + r, jo)] = f2bf(seluf_(acc[r] + o3b));
            }
            __syncthreads();
            // L4 (BB); prefetch next L1
            loadB<WBF>(BA, wsO1, oW1, jo, kb);
            acc = mfma8(T1B, BB, lm, kb);
            if (act) {
#pragma unroll
                for (int r = 0; r < 4; ++r) {
                    const int row = er2 * 4 + r;
                    const float kc = acc[r] + o4b;
                    const float yv = h0[row][jo];
                    float sm;
                    switch (stage) {
                    case 0: k1[r] = kc; sm = A21 * kc; break;
                    case 1: k2[r] = kc; sm = fmaf(A32, kc, A31 * k1[r]); break;
                    case 2: k3[r] = kc; sm = fmaf(A43, kc, fmaf(A42, k2[r], A41 * k1[r])); break;
                    case 3: k4[r] = kc; sm = fmaf(A54, kc, fmaf(A53, k3[r], fmaf(A52, k2[r], A51 * k1[r]))); break;
                    case 4: k5[r] = kc; sm = fmaf(A65, kc, fmaf(A64, k4[r],
                                     fmaf(A63, k3[r], fmaf(A62, k2[r], A61 * k1[r])))); break;
                    default: k6[r] = kc; sm = fmaf(B6f, kc, fmaf(B5f, k5[r],
                                      fmaf(B4f, k4[r], fmaf(B3f, k3[r], B1f * k1[r])))); break;
                    }
                    const float yn = fmaf(dtv[r], sm, yv);
                    if (stage < 5) {
                        YTB[midx(row, jo)] = f2bf(yn);
                    } else {
                        h0[row][jo] = yn;
                        YBF[midx(row, jo)] = f2bf(yn);
                    }
                }
            }
            __syncthreads();
        }
    }

    // ---- output head ----
#pragma unroll 1
    for (int rp4 = 0; rp4 < 2; ++rp4) {
        const int R = rp4 * 4 + (tid >> 8);
        red[tid] = h0[R][t8] * outW[t8];
        __syncthreads();
        for (int sw = 128; sw > 0; sw >>= 1) {
            if (t8 < sw) red[tid] += red[tid + sw];
            __syncthreads();
        }
        if (t8 == 0) {
            float acc = red[tid] + outb[0];
#pragma unroll
            for (int mm = 0; mm < 4; ++mm) acc = fmaf(meta_s[R][mm], outW[HD + mm], acc);
            out[b0 + R] = acc;
        }
        __syncthreads();
    }
}

extern "C" void kernel_launch(void* const* d_in, const int* in_sizes, int n_in,
                              void* d_out, int out_size, void* d_ws, size_t ws_size,
                              hipStream_t stream) {
    const float* x    = (const float*)d_in[0];
    const float* meta = (const float*)d_in[1];
    const float* W_ih = (const float*)d_in[2];
    const float* W_hh = (const float*)d_in[3];
    const float* b_ih = (const float*)d_in[4];
    const float* b_hh = (const float*)d_in[5];
    const float* eW1  = (const float*)d_in[6];
    const float* eb1  = (const float*)d_in[7];
    const float* eW2  = (const float*)d_in[8];
    const float* eb2  = (const float*)d_in[9];
    const float* oW1  = (const float*)d_in[10];
    const float* ob1  = (const float*)d_in[11];
    const float* oW2  = (const float*)d_in[12];
    const float* ob2  = (const float*)d_in[13];
    const float* oW3  = (const float*)d_in[14];
    const float* ob3  = (const float*)d_in[15];
    const float* oW4  = (const float*)d_in[16];
    const float* ob4  = (const float*)d_in[17];
    const float* outW = (const float*)d_in[18];
    const float* outb = (const float*)d_in[19];

    const size_t need = (size_t)458752 * sizeof(ushort_t);   // 896 KB
    const bool wbf = (d_ws != nullptr) && (ws_size >= need);

    if (wbf) {
        cvt_k<<<1792, 256, 0, stream>>>(oW1, oW2, oW3, oW4, W_hh, (ushort_t*)d_ws);
        fused_kernel<1><<<BSZ / RB, TB, 0, stream>>>(x, meta, W_ih, W_hh, b_ih, b_hh,
                                                     eW1, eb1, eW2, eb2,
                                                     oW1, ob1, oW2, ob2, oW3, ob3, oW4, ob4,
                                                     outW, outb, (const ushort_t*)d_ws,
                                                     (float*)d_out);
    } else {
        fused_kernel<0><<<BSZ / RB, TB, 0, stream>>>(x, meta, W_ih, W_hh, b_ih, b_hh,
                                                     eW1, eb1, eW2, eb2,
                                                     oW1, ob1, oW2, ob2, oW3, ob3, oW4, ob4,
                                                     outW, outb, (const ushort_t*)nullptr,
                                                     (float*)d_out);
    }
}

// Round 16
// 2669.910 us; speedup vs baseline: 2.9227x; 1.0201x over previous
//
#include <hip/hip_runtime.h>
#include <math.h>

#define HD   256
#define RB   8      // batch rows per block -> grid 256 = 1 block/CU
#define TB   1024   // 16 waves, 4/SIMD
#define TT   64
#define NST  32
#define BSZ  2048

typedef __attribute__((ext_vector_type(8))) short short8;
typedef __attribute__((ext_vector_type(4))) float f32x4;
typedef unsigned short ushort_t;

// ---------------- math helpers ----------------
__device__ __forceinline__ float sigmoidf_(float x) {
    return 1.0f / (1.0f + __expf(-x));
}
__device__ __forceinline__ float tanhf_(float x) {
    float e = __expf(2.0f * x);
    return 1.0f - 2.0f / (e + 1.0f);
}
__device__ __forceinline__ float seluf_(float x) {
    const float a = 1.6732632423543772f, s = 1.0507009873554805f;
    return x > 0.0f ? s * x : s * a * (__expf(x) - 1.0f);
}
__device__ __forceinline__ float erfinvf_(float x) {
    float w = -log1pf(-x * x);
    float p;
    if (w < 5.0f) {
        w -= 2.5f;
        p = 2.81022636e-08f;
        p = fmaf(p, w, 3.43273939e-07f);
        p = fmaf(p, w, -3.5233877e-06f);
        p = fmaf(p, w, -4.39150654e-06f);
        p = fmaf(p, w, 0.00021858087f);
        p = fmaf(p, w, -0.00125372503f);
        p = fmaf(p, w, -0.00417768164f);
        p = fmaf(p, w, 0.246640727f);
        p = fmaf(p, w, 1.50140941f);
    } else {
        w = sqrtf(w) - 3.0f;
        p = -0.000200214257f;
        p = fmaf(p, w, 0.000100950558f);
        p = fmaf(p, w, 0.00134934322f);
        p = fmaf(p, w, -0.00367342844f);
        p = fmaf(p, w, 0.00573950773f);
        p = fmaf(p, w, -0.0076224613f);
        p = fmaf(p, w, 0.00943887047f);
        p = fmaf(p, w, 1.00167406f);
        p = fmaf(p, w, 2.83297682f);
    }
    return p * x;
}

#define TF_ROUND(x0, x1, R) { x0 += x1; x1 = (x1 << (R)) | (x1 >> (32 - (R))); x1 ^= x0; }

__device__ __forceinline__ void threefry_(unsigned c0, unsigned c1, unsigned& r0, unsigned& r1) {
    const unsigned ks0 = 0u, ks1 = 42u, ks2 = 0x1BD11BDAu ^ 0u ^ 42u;
    unsigned x0 = c0 + ks0, x1 = c1 + ks1;
    TF_ROUND(x0,x1,13) TF_ROUND(x0,x1,15) TF_ROUND(x0,x1,26) TF_ROUND(x0,x1,6)
    x0 += ks1; x1 += ks2 + 1u;
    TF_ROUND(x0,x1,17) TF_ROUND(x0,x1,29) TF_ROUND(x0,x1,16) TF_ROUND(x0,x1,24)
    x0 += ks2; x1 += ks0 + 2u;
    TF_ROUND(x0,x1,13) TF_ROUND(x0,x1,15) TF_ROUND(x0,x1,26) TF_ROUND(x0,x1,6)
    x0 += ks0; x1 += ks1 + 3u;
    TF_ROUND(x0,x1,17) TF_ROUND(x0,x1,29) TF_ROUND(x0,x1,16) TF_ROUND(x0,x1,24)
    x0 += ks1; x1 += ks2 + 4u;
    TF_ROUND(x0,x1,13) TF_ROUND(x0,x1,15) TF_ROUND(x0,x1,26) TF_ROUND(x0,x1,6)
    x0 += ks2; x1 += ks0 + 5u;
    r0 = x0; r1 = x1;
}

// eps[i]: bits = o0 ^ o1 of threefry2x32(key(0,42), (0, i))  [verified round 5]
__device__ __forceinline__ float jax_normal_(unsigned i) {
    unsigned o0, o1;
    threefry_(0u, i, o0, o1);
    unsigned bits = o0 ^ o1;
    unsigned fb = (bits >> 9) | 0x3F800000u;
    float f = __uint_as_float(fb) - 1.0f;
    const float lo = -0.99999994f;
    float u = f * 2.0f + lo;
    u = fmaxf(lo, u);
    return 1.41421356237f * erfinvf_(u);
}

// fp32 -> bf16 RNE
__device__ __forceinline__ ushort_t f2bf(float f) {
    unsigned u = __float_as_uint(f);
    return (ushort_t)((u + 0x7FFFu + ((u >> 16) & 1u)) >> 16);
}

// swizzled bf16 mirror index (ushort units): row stride 256, 16B-chunk XOR swizzle
__device__ __forceinline__ int midx(int row, int k) {
    int chunk = k >> 3;
    return row * 256 + (((chunk ^ (row & 7)) << 3) | (k & 7));
}

// bf16 weight fragment load (WBF=1: from bf16 blob; else convert fp32 inline)
template<int WBF>
__device__ __forceinline__ short8 ldw(const ushort_t* __restrict__ Wbf,
                                      const float* __restrict__ Wf,
                                      int row, int k0) {
    if (WBF) {
        return *(const short8*)(Wbf + (size_t)row * 256 + k0);
    } else {
        const float4 w0 = *(const float4*)(Wf + (size_t)row * 256 + k0);
        const float4 w1 = *(const float4*)(Wf + (size_t)row * 256 + k0 + 4);
        union { ushort_t u[8]; short8 v; } bb;
        bb.u[0] = f2bf(w0.x); bb.u[1] = f2bf(w0.y); bb.u[2] = f2bf(w0.z); bb.u[3] = f2bf(w0.w);
        bb.u[4] = f2bf(w1.x); bb.u[5] = f2bf(w1.y); bb.u[6] = f2bf(w1.z); bb.u[7] = f2bf(w1.w);
        return bb.v;
    }
}

typedef const float (*cmat)[HD];

// ---------------- fp32 quad-coop k-quarter qmm (encoder only; verified R12) ----------------
__device__ __forceinline__ void qmm(const float4* __restrict__ W4, cmat in,
                                    float& r0, float& r1,
                                    const int oj, const int s, const int kh, const int t8,
                                    float (*__restrict__ part)[4][RB][256], const int pb)
{
    float a0[RB], a1[RB], a2[RB], a3[RB];
#pragma unroll
    for (int r = 0; r < RB; ++r) { a0[r] = 0.f; a1[r] = 0.f; a2[r] = 0.f; a3[r] = 0.f; }
    const float4* wp = W4 + (size_t)oj * 64 + kh * 16 + s;
#pragma unroll 2
    for (int g = 0; g < 4; ++g) {
        const float4 w0 = wp[g * 4];
        const float4 w1 = wp[g * 4 + 4096];
        const float4 w2 = wp[g * 4 + 8192];
        const float4 w3 = wp[g * 4 + 12288];
        const int ko = kh * 64 + g * 16 + s * 4;
#pragma unroll
        for (int r = 0; r < RB; ++r) {
            const float4 av = *(const float4*)(&in[r][ko]);
            a0[r] = fmaf(av.w, w0.w, fmaf(av.z, w0.z, fmaf(av.y, w0.y, fmaf(av.x, w0.x, a0[r]))));
            a1[r] = fmaf(av.w, w1.w, fmaf(av.z, w1.z, fmaf(av.y, w1.y, fmaf(av.x, w1.x, a1[r]))));
            a2[r] = fmaf(av.w, w2.w, fmaf(av.z, w2.z, fmaf(av.y, w2.y, fmaf(av.x, w2.x, a2[r]))));
            a3[r] = fmaf(av.w, w3.w, fmaf(av.z, w3.z, fmaf(av.y, w3.y, fmaf(av.x, w3.x, a3[r]))));
        }
    }
    float mine[RB];
#pragma unroll
    for (int r = 0; r < RB; ++r) {
        float v0 = a0[r]; v0 += __shfl_xor(v0, 1); v0 += __shfl_xor(v0, 2);
        float v1 = a1[r]; v1 += __shfl_xor(v1, 1); v1 += __shfl_xor(v1, 2);
        float v2 = a2[r]; v2 += __shfl_xor(v2, 1); v2 += __shfl_xor(v2, 2);
        float v3 = a3[r]; v3 += __shfl_xor(v3, 1); v3 += __shfl_xor(v3, 2);
        mine[r] = (s == 0) ? v0 : (s == 1) ? v1 : (s == 2) ? v2 : v3;
    }
    const int R0 = kh * 2, R1 = R0 + 1;
#pragma unroll
    for (int r = 0; r < RB; ++r) {
        if (r != R0 && r != R1) part[pb][kh][r][t8] = mine[r];
    }
    __syncthreads();
    float s0 = mine[R0], s1 = mine[R1];
#pragma unroll
    for (int q = 1; q < 4; ++q) {
        const int qq = (kh + q) & 3;
        s0 += part[pb][qq][R0][t8];
        s1 += part[pb][qq][R1][t8];
    }
    r0 = s0; r1 = s1;
}

// MFMA over K=256 with preloaded B fragments
__device__ __forceinline__ f32x4 mfma8(const ushort_t* __restrict__ inbf,
                                       const short8 (&B)[8], const int lm, const int kb) {
    f32x4 acc = {0.f, 0.f, 0.f, 0.f};
#pragma unroll
    for (int kt = 0; kt < 8; ++kt) {
        short8 a = *(const short8*)(inbf + midx(lm, kt * 32 + kb * 8));
        acc = __builtin_amdgcn_mfma_f32_16x16x32_bf16(a, B[kt], acc, 0, 0, 0);
    }
    return acc;
}

template<int WBF>
__device__ __forceinline__ void loadB(short8 (&B)[8], const ushort_t* __restrict__ Wbf,
                                      const float* __restrict__ Wf, const int jo, const int kb) {
#pragma unroll
    for (int kt = 0; kt < 8; ++kt)
        B[kt] = ldw<WBF>(Wbf, Wf, jo, kt * 32 + kb * 8);
}

// ---------------- weight bf16 conversion prepass ----------------
// layout: [0,64K) O1 | [64K,128K) O2 | [128K,192K) O3 | [192K,256K) O4 | [256K,448K) Whh
__global__ void cvt_k(const float* __restrict__ o1, const float* __restrict__ o2,
                      const float* __restrict__ o3, const float* __restrict__ o4,
                      const float* __restrict__ whh, ushort_t* __restrict__ out) {
    int i = blockIdx.x * blockDim.x + threadIdx.x;
    if (i < 262144) {
        int m = i >> 16, r = i & 65535;
        const float* s = (m == 0) ? o1 : (m == 1) ? o2 : (m == 2) ? o3 : o4;
        out[i] = f2bf(s[r]);
    } else if (i < 458752) {
        out[i] = f2bf(whh[i - 262144]);
    }
}

// ---------------- fused pipeline kernel ----------------
// Register budget note (R15 lesson): TB=1024 + 127KB LDS -> 1 block/CU = 4 waves/SIMD
// -> 128 regs/lane TOTAL (unified VGPR+AGPR). Accumulators eat the AGPR side, leaving
// ~64 arch VGPRs. R14/R15 demand (~120 arch: BA+BB+k1..k6) spilled 961 MB to scratch.
// Fix: single B buffer (loadB AFTER consumption) + k1..k6 in LDS (aliased onto part[],
// dead after encoder). Demand ~57 arch -> no spill.
template<int WBF>
__global__ __launch_bounds__(TB, 4) void fused_kernel(
    const float* __restrict__ x,
    const float* __restrict__ meta,
    const float* __restrict__ W_ih,
    const float* __restrict__ W_hh,
    const float* __restrict__ b_ih,
    const float* __restrict__ b_hh,
    const float* __restrict__ eW1,
    const float* __restrict__ eb1,
    const float* __restrict__ eW2,
    const float* __restrict__ eb2,
    const float* __restrict__ oW1, const float* __restrict__ ob1,
    const float* __restrict__ oW2, const float* __restrict__ ob2,
    const float* __restrict__ oW3, const float* __restrict__ ob3,
    const float* __restrict__ oW4, const float* __restrict__ ob4,
    const float* __restrict__ outW,
    const float* __restrict__ outb,
    const ushort_t* __restrict__ wsbf,
    float* __restrict__ out)
{
    const int tid = threadIdx.x;
    // encoder fp32-qmm mapping
    const int kh  = tid >> 8;
    const int t8  = tid & 255;
    const int oj  = t8 >> 2;
    const int sq  = t8 & 3;
    const int jj  = oj + 64 * sq;
    const int R0q = kh * 2, R1q = R0q + 1;
    // MFMA mapping
    const int l   = tid & 63;
    const int w   = tid >> 6;            // wave / n-tile base
    const int lm  = l & 15;              // A batch-row / B out-col within tile
    const int kb  = l >> 4;              // k-slice
    const int jo  = w * 16 + lm;         // owned output col (0..255)
    const int er2 = (l >> 4) & 1;        // epilogue row group
    const bool act = (l < 32);
    const int b0  = blockIdx.x * RB;

    __shared__ float h0[RB][HD];                    // fp32 h / y master
    __shared__ float tA[RB][HD];
    __shared__ float xall[RB][TT * 4];
    __shared__ float part[2][4][RB][256];           // 64 KB (encoder; k-store in ODE)
    __shared__ float red[TB];
    __shared__ __align__(16) ushort_t mir[4][16][256];  // 32 KB bf16 mirrors
    __shared__ float meta_s[RB][4];
    __shared__ float dt_s[RB];

    const float4* E1f4 = (const float4*)eW1;
    const float4* E2f4 = (const float4*)eW2;
    ushort_t* YBF = &mir[0][0][0];
    ushort_t* YTB = &mir[1][0][0];
    ushort_t* T1B = &mir[2][0][0];
    ushort_t* T2B = &mir[3][0][0];
    const ushort_t* wsO1 = wsbf;
    const ushort_t* wsO2 = wsbf + 65536;
    const ushort_t* wsO3 = wsbf + 131072;
    const ushort_t* wsO4 = wsbf + 196608;
    const ushort_t* wsWhh = wsbf + 262144;
    float* kst = &part[0][0][0][0];      // ODE k-store: kst[s*2048 + row*256 + jo], 48 KB

    cmat tAc = (cmat)tA;

    int pb = 0;
    auto QMM = [&](const float4* W4p, cmat inp, float& q0, float& q1) {
        qmm(W4p, inp, q0, q1, oj, sq, kh, t8, part, pb);
        pb ^= 1;
    };

    // ---- stage x, meta; zero h0 and mirrors ----
#pragma unroll
    for (int i = 0; i < 2; ++i) {
        int idx = tid + i * TB;
        int r = idx >> 8, c = idx & 255;
        xall[r][c] = x[(size_t)(b0 + r) * 256 + c];
    }
    if (tid < RB * 4) { int r = tid >> 2, mm = tid & 3; meta_s[r][mm] = meta[(b0 + r) * 4 + mm]; }
    if (tid < 2 * HD) { int r = tid >> 8, c = tid & 255;
        h0[r][c] = 0.0f; h0[r + 2][c] = 0.0f; h0[r + 4][c] = 0.0f; h0[r + 6][c] = 0.0f; }
    {
        unsigned* mz = (unsigned*)&mir[0][0][0];   // 8192 u32 = 32 KB
#pragma unroll
        for (int i = 0; i < 8; ++i) mz[tid + i * TB] = 0u;
    }
    __syncthreads();
    if (tid < RB) dt_s[tid] = (xall[tid][TT * 4 - 4] - xall[tid][0]) * (1.0f / (float)NST);

    // ---- GRU per-lane x-side constants for owned col jo ----
    float wxr[4], wxz[4], wxn[4];
#pragma unroll
    for (int d = 0; d < 4; ++d) {
        wxr[d] = W_ih[(size_t)jo * 8 + d];
        wxz[d] = W_ih[(size_t)(jo + 256) * 8 + d];
        wxn[d] = W_ih[(size_t)(jo + 512) * 8 + d];
    }
    float base_r[4], base_z[4], base_xn[4];
    {
        float mwr[4], mwz[4], mwn[4];
#pragma unroll
        for (int mm = 0; mm < 4; ++mm) {
            mwr[mm] = W_ih[(size_t)jo * 8 + 4 + mm];
            mwz[mm] = W_ih[(size_t)(jo + 256) * 8 + 4 + mm];
            mwn[mm] = W_ih[(size_t)(jo + 512) * 8 + 4 + mm];
        }
        const float bir = b_ih[jo], biz = b_ih[jo + 256], bin_ = b_ih[jo + 512];
        const float bhr = b_hh[jo], bhz = b_hh[jo + 256];
#pragma unroll
        for (int r = 0; r < 4; ++r) {
            const int R = er2 * 4 + r;
            float sr = bir + bhr, sz = biz + bhz, sn = bin_;
#pragma unroll
            for (int mm = 0; mm < 4; ++mm) {
                float mv = meta_s[R][mm];
                sr = fmaf(mv, mwr[mm], sr);
                sz = fmaf(mv, mwz[mm], sz);
                sn = fmaf(mv, mwn[mm], sn);
            }
            base_r[r] = sr; base_z[r] = sz; base_xn[r] = sn;
        }
    }
    const float bhn = b_hh[512 + jo];

    // ---- GRU: 64 steps, MFMA bf16, mirror ping-pong, ONE barrier/step ----
    int p = 0;
#pragma unroll 1
    for (int t = 0; t < TT; ++t) {
        const ushort_t* YHp = &mir[p][0][0];
        f32x4 aR = {0.f,0.f,0.f,0.f}, aZ = {0.f,0.f,0.f,0.f}, aN = {0.f,0.f,0.f,0.f};
#pragma unroll 2
        for (int kt = 0; kt < 8; ++kt) {
            const int k0 = kt * 32 + kb * 8;
            short8 a  = *(const short8*)(YHp + midx(lm, k0));
            short8 br = ldw<WBF>(wsWhh, W_hh, jo, k0);
            short8 bz = ldw<WBF>(wsWhh, W_hh, jo + 256, k0);
            short8 bn = ldw<WBF>(wsWhh, W_hh, jo + 512, k0);
            aR = __builtin_amdgcn_mfma_f32_16x16x32_bf16(a, br, aR, 0, 0, 0);
            aZ = __builtin_amdgcn_mfma_f32_16x16x32_bf16(a, bz, aZ, 0, 0, 0);
            aN = __builtin_amdgcn_mfma_f32_16x16x32_bf16(a, bn, aN, 0, 0, 0);
        }
        if (act) {
            ushort_t* YHn = &mir[p ^ 1][0][0];
#pragma unroll
            for (int r = 0; r < 4; ++r) {
                const int R = er2 * 4 + r;
                float xr = base_r[r], xz = base_z[r], xn = base_xn[r];
#pragma unroll
                for (int d = 0; d < 4; ++d) {
                    float xv = xall[R][t * 4 + d];
                    xr = fmaf(xv, wxr[d], xr);
                    xz = fmaf(xv, wxz[d], xz);
                    xn = fmaf(xv, wxn[d], xn);
                }
                float rg = sigmoidf_(xr + aR[r]);
                float zg = sigmoidf_(xz + aZ[r]);
                float ng = tanhf_(fmaf(rg, aN[r] + bhn, xn));
                float hp = h0[R][jo];
                float hnew = fmaf(zg, hp - ng, ng);
                h0[R][jo] = hnew;
                YHn[midx(R, jo)] = f2bf(hnew);
            }
        }
        __syncthreads();
        p ^= 1;
    }

    // ---- encoder + sample y0 (fp32, exact) ----
    {
        float a0, a1;
        QMM(E1f4, (cmat)h0, a0, a1);
        const float eb1j = eb1[jj];
        tA[R0q][jj] = fmaxf(a0 + eb1j, 0.0f);
        tA[R1q][jj] = fmaxf(a1 + eb1j, 0.0f);
        __syncthreads();

        float aM0, aM1, aS0, aS1;
        QMM(E2f4,            tAc, aM0, aM1);
        QMM(E2f4 + 256 * 64, tAc, aS0, aS1);
        const float bm = eb2[jj], bs = eb2[256 + jj];
        float e0 = jax_normal_((unsigned)((b0 + R0q) * HD + jj));
        float e1 = jax_normal_((unsigned)((b0 + R1q) * HD + jj));
        float y0a = fmaf(e0, aS0 + bs, aM0 + bm);
        float y0b = fmaf(e1, aS1 + bs, aM1 + bm);
        h0[R0q][jj] = y0a;
        h0[R1q][jj] = y0b;
        YBF[midx(R0q, jj)] = f2bf(y0a);
        YBF[midx(R1q, jj)] = f2bf(y0b);
        __syncthreads();
    }

    // ---- dopri5: MFMA bf16 ODE; k's in LDS (kst), single B buffer ----
    const float A21 = (float)(1.0/5.0);
    const float A31 = (float)(3.0/40.0),      A32 = (float)(9.0/40.0);
    const float A41 = (float)(44.0/45.0),     A42 = (float)(-56.0/15.0),    A43 = (float)(32.0/9.0);
    const float A51 = (float)(19372.0/6561.0),A52 = (float)(-25360.0/2187.0),
                A53 = (float)(64448.0/6561.0),A54 = (float)(-212.0/729.0);
    const float A61 = (float)(9017.0/3168.0), A62 = (float)(-355.0/33.0),
                A63 = (float)(46732.0/5247.0),A64 = (float)(49.0/176.0),    A65 = (float)(-5103.0/18656.0);
    const float B1f = (float)(35.0/384.0),    B3f = (float)(500.0/1113.0),  B4f = (float)(125.0/192.0),
                B5f = (float)(-2187.0/6784.0),B6f = (float)(11.0/84.0);

    const float o1b = ob1[jo], o2b = ob2[jo], o3b = ob3[jo], o4b = ob4[jo];
    float dtv[4];
    if (act) {
#pragma unroll
        for (int r = 0; r < 4; ++r) dtv[r] = dt_s[er2 * 4 + r];
    }

    short8 BA[8];
    loadB<WBF>(BA, wsO1, oW1, jo, kb);    // prologue: L1 weights

#pragma unroll 1
    for (int st = 0; st < NST; ++st) {
#pragma unroll 1
        for (int stage = 0; stage < 6; ++stage) {
            const ushort_t* in0 = (stage == 0) ? YBF : YTB;
            // L1 (BA holds O1); then reload BA with O2
            f32x4 acc = mfma8(in0, BA, lm, kb);
            loadB<WBF>(BA, wsO2, oW2, jo, kb);
            if (act) {
#pragma unroll
                for (int r = 0; r < 4; ++r)
                    T1B[midx(er2 * 4 + r, jo)] = f2bf(seluf_(acc[r] + o1b));
            }
            __syncthreads();
            // L2
            acc = mfma8(T1B, BA, lm, kb);
            loadB<WBF>(BA, wsO3, oW3, jo, kb);
            if (act) {
#pragma unroll
                for (int r = 0; r < 4; ++r)
                    T2B[midx(er2 * 4 + r, jo)] = f2bf(seluf_(acc[r] + o2b));
            }
            __syncthreads();
            // L3
            acc = mfma8(T2B, BA, lm, kb);
            loadB<WBF>(BA, wsO4, oW4, jo, kb);
            if (act) {
#pragma unroll
                for (int r = 0; r < 4; ++r)
                    T1B[midx(er2 * 4 + r, jo)] = f2bf(seluf_(acc[r] + o3b));
            }
            __syncthreads();
            // L4; reload BA with O1 for next stage
            acc = mfma8(T1B, BA, lm, kb);
            loadB<WBF>(BA, wsO1, oW1, jo, kb);
            if (act) {
#pragma unroll
                for (int r = 0; r < 4; ++r) {
                    const int row = er2 * 4 + r;
                    const int ki = row * 256 + jo;
                    const float kc = acc[r] + o4b;
                    kst[stage * 2048 + ki] = kc;
                    const float yv = h0[row][jo];
                    float sm;
                    switch (stage) {
                    case 0:
                        sm = A21 * kc;
                        break;
                    case 1: {
                        float k1v = kst[ki];
                        sm = fmaf(A32, kc, A31 * k1v);
                        break; }
                    case 2: {
                        float k1v = kst[ki], k2v = kst[2048 + ki];
                        sm = fmaf(A43, kc, fmaf(A42, k2v, A41 * k1v));
                        break; }
                    case 3: {
                        float k1v = kst[ki], k2v = kst[2048 + ki], k3v = kst[4096 + ki];
                        sm = fmaf(A54, kc, fmaf(A53, k3v, fmaf(A52, k2v, A51 * k1v)));
                        break; }
                    case 4: {
                        float k1v = kst[ki], k2v = kst[2048 + ki];
                        float k3v = kst[4096 + ki], k4v = kst[6144 + ki];
                        sm = fmaf(A65, kc, fmaf(A64, k4v,
                             fmaf(A63, k3v, fmaf(A62, k2v, A61 * k1v))));
                        break; }
                    default: {
                        float k1v = kst[ki], k3v = kst[4096 + ki];
                        float k4v = kst[6144 + ki], k5v = kst[8192 + ki];
                        sm = fmaf(B6f, kc, fmaf(B5f, k5v,
                             fmaf(B4f, k4v, fmaf(B3f, k3v, B1f * k1v))));
                        break; }
                    }
                    const float yn = fmaf(dtv[r], sm, yv);
                    if (stage < 5) {
                        YTB[midx(row, jo)] = f2bf(yn);
                    } else {
                        h0[row][jo] = yn;
                        YBF[midx(row, jo)] = f2bf(yn);
                    }
                }
            }
            __syncthreads();
        }
    }

    // ---- output head ----
#pragma unroll 1
    for (int rp4 = 0; rp4 < 2; ++rp4) {
        const int R = rp4 * 4 + (tid >> 8);
        red[tid] = h0[R][t8] * outW[t8];
        __syncthreads();
        for (int sw = 128; sw > 0; sw >>= 1) {
            if (t8 < sw) red[tid] += red[tid + sw];
            __syncthreads();
        }
        if (t8 == 0) {
            float acc = red[tid] + outb[0];
#pragma unroll
            for (int mm = 0; mm < 4; ++mm) acc = fmaf(meta_s[R][mm], outW[HD + mm], acc);
            out[b0 + R] = acc;
        }
        __syncthreads();
    }
}

extern "C" void kernel_launch(void* const* d_in, const int* in_sizes, int n_in,
                              void* d_out, int out_size, void* d_ws, size_t ws_size,
                              hipStream_t stream) {
    const float* x    = (const float*)d_in[0];
    const float* meta = (const float*)d_in[1];
    const float* W_ih = (const float*)d_in[2];
    const float* W_hh = (const float*)d_in[3];
    const float* b_ih = (const float*)d_in[4];
    const float* b_hh = (const float*)d_in[5];
    const float* eW1  = (const float*)d_in[6];
    const float* eb1  = (const float*)d_in[7];
    const float* eW2  = (const float*)d_in[8];
    const float* eb2  = (const float*)d_in[9];
    const float* oW1  = (const float*)d_in[10];
    const float* ob1  = (const float*)d_in[11];
    const float* oW2  = (const float*)d_in[12];
    const float* ob2  = (const float*)d_in[13];
    const float* oW3  = (const float*)d_in[14];
    const float* ob3  = (const float*)d_in[15];
    const float* oW4  = (const float*)d_in[16];
    const float* ob4  = (const float*)d_in[17];
    const float* outW = (const float*)d_in[18];
    const float* outb = (const float*)d_in[19];

    const size_t need = (size_t)458752 * sizeof(ushort_t);   // 896 KB
    const bool wbf = (d_ws != nullptr) && (ws_size >= need);

    if (wbf) {
        cvt_k<<<1792, 256, 0, stream>>>(oW1, oW2, oW3, oW4, W_hh, (ushort_t*)d_ws);
        fused_kernel<1><<<BSZ / RB, TB, 0, stream>>>(x, meta, W_ih, W_hh, b_ih, b_hh,
                                                     eW1, eb1, eW2, eb2,
                                                     oW1, ob1, oW2, ob2, oW3, ob3, oW4, ob4,
                                                     outW, outb, (const ushort_t*)d_ws,
                                                     (float*)d_out);
    } else {
        fused_kernel<0><<<BSZ / RB, TB, 0, stream>>>(x, meta, W_ih, W_hh, b_ih, b_hh,
                                                     eW1, eb1, eW2, eb2,
                                                     oW1, ob1, oW2, ob2, oW3, ob3, oW4, ob4,
                                                     outW, outb, (const ushort_t*)nullptr,
                                                     (float*)d_out);
    }
}